// Round 9
// baseline (2086.022 us; speedup 1.0000x reference)
//
#include <hip/hip_runtime.h>
#include <hip/hip_bf16.h>

// ---------------- problem constants ----------------
#define HID 128
static const int N_NODES = 50000;
static const int N_EDGES = 20000;
static const int M_COPIES = 400000;
static const int L_EDGES = 800000;
static const int NBATCH = 32;
static const int NCLS = 10;
#define INV_STD 0.9999950000374997f   // 1/sqrt(1+1e-5)

typedef __attribute__((ext_vector_type(4))) float f32x4;
typedef __attribute__((ext_vector_type(8))) short short8;      // 8 bf16 lanes
typedef __attribute__((ext_vector_type(8))) unsigned short ushort8;
typedef __attribute__((ext_vector_type(4))) unsigned short u16x4;  // NOTE: 'ushort4' collides with HIP header

// xor-swizzled LDS chunk address (in shorts): row-major rows of 16 chunks,
// chunk column permuted by row to spread banks for both write and read patterns
#define XADDR(r, g) ((((r) << 4) + ((g) ^ ((r) & 15))) << 3)

__device__ __forceinline__ float bf2f(unsigned short u) {
    union { unsigned u; float f; } v; v.u = ((unsigned)u) << 16; return v.f;
}
__device__ __forceinline__ unsigned short f2bf(float f) {
    union { float f; unsigned u; } v; v.f = f;
    unsigned r = v.u + 0x7FFFu + ((v.u >> 16) & 1u);   // RNE
    return (unsigned short)(r >> 16);
}
__device__ __forceinline__ void gatomic_add(float* p, float v) {
    unsafeAtomicAdd(p, v);
}

// ---------------- weight prep: Wt[mat][n][k] = bf16(W[mat][k][n]) ----------------
__global__ __launch_bounds__(256) void prep_w(const float* __restrict__ We,
                                              const float* __restrict__ Wg,
                                              unsigned short* __restrict__ Wt) {
    int t = blockIdx.x * 256 + threadIdx.x;       // 17*16384
    if (t >= 17 * 16384) return;
    int mat = t >> 14, rem = t & 16383;
    int n = rem >> 7, k = rem & 127;
    const float* src = (mat == 0) ? We : (Wg + (size_t)(mat - 1) * 16384);
    Wt[t] = f2bf(src[k * 128 + n]);
}

// ---------------- CSR build ----------------
__global__ __launch_bounds__(256) void hist_k(const int* __restrict__ idx, int n,
                                              int* __restrict__ cnt) {
    int t = blockIdx.x * 256 + threadIdx.x;
    if (t < n) atomicAdd(&cnt[idx[t]], 1);
}

__global__ __launch_bounds__(256) void scan1_k(int* __restrict__ a, int n,
                                               int* __restrict__ part) {
    __shared__ int s[256];
    int i = blockIdx.x * 256 + threadIdx.x;
    int v = (i < n) ? a[i] : 0;
    s[threadIdx.x] = v;
    __syncthreads();
#pragma unroll
    for (int d = 1; d < 256; d <<= 1) {
        int t = (threadIdx.x >= d) ? s[threadIdx.x - d] : 0;
        __syncthreads();
        s[threadIdx.x] += t;
        __syncthreads();
    }
    if (i < n) a[i] = s[threadIdx.x] - v;
    if (threadIdx.x == 255) part[blockIdx.x] = s[255];
}

__global__ __launch_bounds__(256) void scan2_k(int* __restrict__ part, int nb) {
    __shared__ int s[256];
    __shared__ int carry;
    if (threadIdx.x == 0) carry = 0;
    __syncthreads();
    for (int base = 0; base < nb; base += 256) {
        int i = base + threadIdx.x;
        int v = (i < nb) ? part[i] : 0;
        s[threadIdx.x] = v;
        __syncthreads();
#pragma unroll
        for (int d = 1; d < 256; d <<= 1) {
            int t = (threadIdx.x >= d) ? s[threadIdx.x - d] : 0;
            __syncthreads();
            s[threadIdx.x] += t;
            __syncthreads();
        }
        if (i < nb) part[i] = carry + s[threadIdx.x] - v;
        __syncthreads();
        if (threadIdx.x == 0) carry += s[255];
        __syncthreads();
    }
}

__global__ __launch_bounds__(256) void scan3_k(int* __restrict__ a, int n,
                                               const int* __restrict__ part) {
    int i = blockIdx.x * 256 + threadIdx.x;
    if (i < n) a[i] += part[blockIdx.x];
}

__global__ __launch_bounds__(256) void fill_edge_k(
    const int* __restrict__ src, const int* __restrict__ dst,
    const int* __restrict__ remap, int n, int* __restrict__ off,
    int* __restrict__ srcs, int* __restrict__ comps) {
    int e = blockIdx.x * 256 + threadIdx.x;
    if (e >= n) return;
    int d = dst[e];
    int pos = atomicAdd(&off[d], 1);
    int s = src[e];
    srcs[pos] = s;
    comps[pos] = remap[s];
}

__global__ __launch_bounds__(256) void fill_pool_k(
    const int* __restrict__ seg, int n, int* __restrict__ off,
    int* __restrict__ items) {
    int m = blockIdx.x * 256 + threadIdx.x;
    if (m >= n) return;
    int pos = atomicAdd(&off[seg[m]], 1);
    items[pos] = m;
}

// ---------------- pool segment sum: out[m]=relu(sum tbl[items]); 4 segs/wave ----------------
__global__ __launch_bounds__(256) void segsum_pool(
    const unsigned* __restrict__ tbl, const int* __restrict__ off,
    const int* __restrict__ items, unsigned* __restrict__ out, int nseg)
{
    int wave = threadIdx.x >> 6, lane = threadIdx.x & 63;
    int mb = blockIdx.x * 16 + wave * 4;
    float a0[4] = {0.f, 0.f, 0.f, 0.f}, a1[4] = {0.f, 0.f, 0.f, 0.f};
    int pos[4], end[4];
#pragma unroll
    for (int i = 0; i < 4; ++i) {
        int m = mb + i;
        if (m < nseg) { pos[i] = (m == 0) ? 0 : off[m - 1]; end[i] = off[m]; }
        else { pos[i] = 0; end[i] = 0; }
    }
    bool more = (pos[0] < end[0]) | (pos[1] < end[1]) | (pos[2] < end[2]) | (pos[3] < end[3]);
    while (more) {
        more = false;
        unsigned v[4]; bool ld[4];
#pragma unroll
        for (int i = 0; i < 4; ++i) {
            ld[i] = pos[i] < end[i];
            if (ld[i]) v[i] = tbl[(size_t)items[pos[i]] * 64 + lane];
        }
#pragma unroll
        for (int i = 0; i < 4; ++i) if (ld[i]) {
            a0[i] += bf2f((unsigned short)(v[i] & 0xffffu));
            a1[i] += bf2f((unsigned short)(v[i] >> 16));
            ++pos[i];
            more = more || (pos[i] < end[i]);
        }
    }
#pragma unroll
    for (int i = 0; i < 4; ++i) {
        int m = mb + i;
        if (m < nseg) {
            float r0 = fmaxf(a0[i], 0.f), r1 = fmaxf(a1[i], 0.f);
            out[(size_t)m * 64 + lane] = (unsigned)f2bf(r0) | ((unsigned)f2bf(r1) << 16);
        }
    }
}

// ---------------- fused GIN conv (operand-swapped MFMAs, swizzled LDS) ----------------
// CONV0: self = self_idx[m], items = comps; final ReLU after BN.
// !CONV0: self = m, items = srcs; no final ReLU. rows multiple of 64.
template<bool CONV0>
__global__ __launch_bounds__(256) void fused_conv(
    const unsigned short* __restrict__ tbl,
    const int* __restrict__ self_idx,
    const int* __restrict__ off, const int* __restrict__ items,
    const float* __restrict__ eps_ptr,
    const unsigned short* __restrict__ W1t, const float* __restrict__ b1,
    const unsigned short* __restrict__ W2t, const float* __restrict__ b2,
    const float* __restrict__ gam, const float* __restrict__ bet,
    unsigned short* __restrict__ out)
{
    __shared__ __align__(16) unsigned short Xs[64 * 16 * 8];   // 16 KB (swizzled)
    __shared__ __align__(16) unsigned short Ws[16 * 128 * 8];  // 32 KB
    __shared__ int meta[192];
    const int tid = threadIdx.x;
    const int row0 = blockIdx.x * 64;

    if (tid < 64) {
        int gr = row0 + tid;
        meta[tid]       = (gr == 0) ? 0 : off[gr - 1];
        meta[64 + tid]  = off[gr];
        meta[128 + tid] = CONV0 ? self_idx[gr] : gr;
    }
    // stage W1
#pragma unroll
    for (int i = 0; i < 8; ++i) {
        int chunk = tid + i * 256;
        int n = chunk >> 4, gg = chunk & 15;
        *(short8*)(Ws + (gg * 128 + n) * 8) = *(const short8*)(W1t + n * 128 + gg * 8);
    }
    __syncthreads();

    // ---- gather: 4 rows per thread, walked jointly (4x MLP) ----
    const float e = 1.0f + eps_ptr[0];
    const int g = tid & 15;
    const int rb = tid >> 4;
    float a[4][8];
    int pos[4], end[4];
#pragma unroll
    for (int i = 0; i < 4; ++i) {
        int r = rb + 16 * i;
        pos[i] = meta[r];
        end[i] = meta[64 + r];
        int self = meta[128 + r];
        ushort8 u = *(const ushort8*)(tbl + (size_t)self * 128 + g * 8);
#pragma unroll
        for (int j = 0; j < 8; ++j) a[i][j] = e * bf2f(u[j]);
    }
    bool more = (pos[0] < end[0]) | (pos[1] < end[1]) | (pos[2] < end[2]) | (pos[3] < end[3]);
    while (more) {
        more = false;
        ushort8 v[4]; bool ld[4];
#pragma unroll
        for (int i = 0; i < 4; ++i) {
            ld[i] = pos[i] < end[i];
            if (ld[i]) v[i] = *(const ushort8*)(tbl + (size_t)items[pos[i]] * 128 + g * 8);
        }
#pragma unroll
        for (int i = 0; i < 4; ++i) if (ld[i]) {
#pragma unroll
            for (int j = 0; j < 8; ++j) a[i][j] += bf2f(v[i][j]);
            ++pos[i];
            more = more || (pos[i] < end[i]);
        }
    }
#pragma unroll
    for (int i = 0; i < 4; ++i) {
        int r = rb + 16 * i;
        ushort8 xv;
#pragma unroll
        for (int j = 0; j < 8; ++j) xv[j] = f2bf(a[i][j]);
        *(ushort8*)(Xs + XADDR(r, g)) = xv;
    }
    __syncthreads();

    const int wave = tid >> 6, lane = tid & 63;
    const int q0 = wave * 16;
    const int ln = lane & 15, quad = lane >> 4;
    const int row = q0 + ln;     // this wave's private X/H row

    // ---- MFMA 1 (swapped): lane holds H[row][p0..p0+3] ----
    f32x4 acc[8];
#pragma unroll
    for (int t = 0; t < 8; ++t) acc[t] = (f32x4){0.f, 0.f, 0.f, 0.f};
#pragma unroll
    for (int kc = 0; kc < 4; ++kc) {
        int gl = kc * 4 + quad;
        short8 xb = *(const short8*)(Xs + XADDR(row, gl));
#pragma unroll
        for (int t = 0; t < 8; ++t) {
            short8 wa = *(const short8*)(Ws + (gl * 128 + t * 16 + ln) * 8);
            acc[t] = __builtin_amdgcn_mfma_f32_16x16x32_bf16(wa, xb, acc[t], 0, 0, 0);
        }
    }
    // h = relu(acc + b1) -> Xs as H[row][p], 4 consecutive channels per reg -> b64 writes
    {
        const int j0 = (quad & 1) * 4;
#pragma unroll
        for (int t = 0; t < 8; ++t) {
            int p0 = t * 16 + quad * 4;
            f32x4 bv = *(const f32x4*)(b1 + p0);
            u16x4 hp;
#pragma unroll
            for (int i = 0; i < 4; ++i) hp[i] = f2bf(fmaxf(acc[t][i] + bv[i], 0.f));
            *(u16x4*)(Xs + XADDR(row, p0 >> 3) + j0) = hp;
        }
    }
    __syncthreads();
    // stage W2
#pragma unroll
    for (int i = 0; i < 8; ++i) {
        int chunk = tid + i * 256;
        int n = chunk >> 4, gg = chunk & 15;
        *(short8*)(Ws + (gg * 128 + n) * 8) = *(const short8*)(W2t + n * 128 + gg * 8);
    }
    __syncthreads();

    // ---- MFMA 2 (swapped): lane holds out[m=row0+row][n0..n0+3] ----
#pragma unroll
    for (int t = 0; t < 8; ++t) acc[t] = (f32x4){0.f, 0.f, 0.f, 0.f};
#pragma unroll
    for (int kc = 0; kc < 4; ++kc) {
        int gl = kc * 4 + quad;
        short8 hb = *(const short8*)(Xs + XADDR(row, gl));
#pragma unroll
        for (int t = 0; t < 8; ++t) {
            short8 wa = *(const short8*)(Ws + (gl * 128 + t * 16 + ln) * 8);
            acc[t] = __builtin_amdgcn_mfma_f32_16x16x32_bf16(wa, hb, acc[t], 0, 0, 0);
        }
    }
    const int m = row0 + row;
#pragma unroll
    for (int t = 0; t < 8; ++t) {
        int n0 = t * 16 + quad * 4;
        f32x4 bv = *(const f32x4*)(b2 + n0);
        f32x4 gv = *(const f32x4*)(gam + n0);
        f32x4 tv = *(const f32x4*)(bet + n0);
        u16x4 op;
#pragma unroll
        for (int i = 0; i < 4; ++i) {
            float h = acc[t][i] + bv[i];
            h = gv[i] * h * INV_STD + tv[i];
            if (CONV0) h = fmaxf(h, 0.f);
            op[i] = f2bf(h);
        }
        *(u16x4*)(out + (size_t)m * 128 + n0) = op;
    }
}

// ---------------- embedding GEMM (f32 in): out = in @ W + b ----------------
__global__ __launch_bounds__(256) void gemm_embed(
    const float* __restrict__ in, const unsigned short* __restrict__ Wt,
    const float* __restrict__ bias, unsigned short* __restrict__ out_bf, int rows)
{
    __shared__ __align__(16) unsigned short Xs[16 * 64 * 8];
    __shared__ __align__(16) unsigned short Ws[16 * 128 * 8];
    int tid = threadIdx.x;
    int row0 = blockIdx.x * 64;
#pragma unroll
    for (int i = 0; i < 8; ++i) {
        int chunk = tid + i * 256;
        int n = chunk >> 4, g = chunk & 15;
        *(short8*)(Ws + (g * 128 + n) * 8) = *(const short8*)(Wt + n * 128 + g * 8);
    }
#pragma unroll
    for (int i = 0; i < 4; ++i) {
        int chunk = tid + i * 256;
        int r = chunk >> 4, g = chunk & 15;
        int gr = row0 + r;
        ushort8 v;
        if (gr < rows) {
            const float* p = in + (size_t)gr * 128 + g * 8;
            f32x4 a0 = *(const f32x4*)p;
            f32x4 a1 = *(const f32x4*)(p + 4);
#pragma unroll
            for (int j = 0; j < 4; ++j) { v[j] = f2bf(a0[j]); v[4 + j] = f2bf(a1[j]); }
        } else {
#pragma unroll
            for (int j = 0; j < 8; ++j) v[j] = 0;
        }
        *(ushort8*)(Xs + (g * 64 + r) * 8) = v;
    }
    __syncthreads();
    int wave = tid >> 6, lane = tid & 63;
    int m0 = wave * 16;
    int ln = lane & 15, quad = lane >> 4;
    f32x4 acc[8];
#pragma unroll
    for (int t = 0; t < 8; ++t) acc[t] = (f32x4){0.f, 0.f, 0.f, 0.f};
#pragma unroll
    for (int kc = 0; kc < 4; ++kc) {
        int g = kc * 4 + quad;
        short8 a = *(const short8*)(Xs + (g * 64 + m0 + ln) * 8);
#pragma unroll
        for (int t = 0; t < 8; ++t) {
            short8 b = *(const short8*)(Ws + (g * 128 + t * 16 + ln) * 8);
            acc[t] = __builtin_amdgcn_mfma_f32_16x16x32_bf16(a, b, acc[t], 0, 0, 0);
        }
    }
#pragma unroll
    for (int t = 0; t < 8; ++t) {
        int col = t * 16 + ln;
        float bi = bias[col];
#pragma unroll
        for (int i = 0; i < 4; ++i) {
            int gr = row0 + m0 + quad * 4 + i;
            if (gr < rows) out_bf[(size_t)gr * 128 + col] = f2bf(acc[t][i] + bi);
        }
    }
}

// ---------------- y projection: y[r][10] (+)= nx[r][:] @ Wp ----------------
template<bool ACCUM>
__global__ __launch_bounds__(256) void proj_y(
    const unsigned short* __restrict__ nx, const float* __restrict__ Wp,
    float* __restrict__ y, int rows)
{
    __shared__ float Wl[HID * NCLS];
    for (int i = threadIdx.x; i < HID * NCLS; i += 256) Wl[i] = Wp[i];
    __syncthreads();
    int r = blockIdx.x * 256 + threadIdx.x;
    if (r >= rows) return;
    float acc[NCLS];
#pragma unroll
    for (int c = 0; c < NCLS; ++c) acc[c] = 0.f;
    const unsigned short* xp = nx + (size_t)r * 128;
#pragma unroll 4
    for (int g = 0; g < 16; ++g) {
        ushort8 u = *(const ushort8*)(xp + g * 8);
#pragma unroll
        for (int j = 0; j < 8; ++j) {
            float xv = bf2f(u[j]);
            const float* w = Wl + (g * 8 + j) * NCLS;
#pragma unroll
            for (int c = 0; c < NCLS; ++c) acc[c] += xv * w[c];
        }
    }
    float* yp = y + (size_t)r * NCLS;
#pragma unroll
    for (int c = 0; c < NCLS; ++c) {
        if (ACCUM) yp[c] += acc[c];
        else yp[c] = acc[c];
    }
}

// ---------------- score scatter: score[b][:] += y[ori[m]][:] ----------------
__global__ __launch_bounds__(256) void score_scatter(
    const float* __restrict__ y, const int* __restrict__ ori,
    const int* __restrict__ batch, float* __restrict__ score)
{
    __shared__ float sc[NBATCH * NCLS];
    for (int i = threadIdx.x; i < NBATCH * NCLS; i += 256) sc[i] = 0.f;
    __syncthreads();
    int stride = gridDim.x * 256;
    for (int m = blockIdx.x * 256 + threadIdx.x; m < M_COPIES; m += stride) {
        int r = ori[m], b = batch[m];
        const float* yp = y + (size_t)r * NCLS;
#pragma unroll
        for (int c = 0; c < NCLS; ++c)
            __hip_atomic_fetch_add(&sc[b * NCLS + c], yp[c],
                                   __ATOMIC_RELAXED, __HIP_MEMORY_SCOPE_WORKGROUP);
    }
    __syncthreads();
    for (int i = threadIdx.x; i < NBATCH * NCLS; i += 256) gatomic_add(score + i, sc[i]);
}

__global__ void score_final(const float* __restrict__ score, const float* __restrict__ bp,
                            float* __restrict__ out)
{
    int t = threadIdx.x;
    if (t >= NBATCH * NCLS) return;
    int c = t % NCLS;
    out[t] = score[t] + bp[c] + bp[NCLS + c] + bp[2 * NCLS + c];
}

__global__ void fill_sentinel(float* out, int n, float enc) {
    int t = blockIdx.x * 64 + threadIdx.x;
    if (t < n) out[t] = enc;
}

// ---------------- helpers ----------------
static inline void build_csr_edge(const int* src, const int* dst, const int* remap,
                                  int nitem, int nseg, int* off, int* part,
                                  int* srcs, int* comps, hipStream_t stream) {
    int nb = (nseg + 255) / 256;
    (void)hipMemsetAsync(off, 0, (size_t)nseg * 4, stream);
    hist_k<<<(nitem + 255) / 256, 256, 0, stream>>>(dst, nitem, off);
    scan1_k<<<nb, 256, 0, stream>>>(off, nseg, part);
    scan2_k<<<1, 256, 0, stream>>>(part, nb);
    scan3_k<<<nb, 256, 0, stream>>>(off, nseg, part);
    fill_edge_k<<<(nitem + 255) / 256, 256, 0, stream>>>(src, dst, remap, nitem, off, srcs, comps);
}
static inline void build_csr_pool(const int* seg, int nitem, int nseg,
                                  int* off, int* part, int* items, hipStream_t stream) {
    int nb = (nseg + 255) / 256;
    (void)hipMemsetAsync(off, 0, (size_t)nseg * 4, stream);
    hist_k<<<(nitem + 255) / 256, 256, 0, stream>>>(seg, nitem, off);
    scan1_k<<<nb, 256, 0, stream>>>(off, nseg, part);
    scan2_k<<<1, 256, 0, stream>>>(part, nb);
    scan3_k<<<nb, 256, 0, stream>>>(off, nseg, part);
    fill_pool_k<<<(nitem + 255) / 256, 256, 0, stream>>>(seg, nitem, off, items);
}

// ---------------- entry ----------------
extern "C" void kernel_launch(void* const* d_in, const int* in_sizes, int n_in,
                              void* d_out, int out_size, void* d_ws, size_t ws_size,
                              hipStream_t stream) {
    const float* x_N    = (const float*)d_in[0];
    const float* We     = (const float*)d_in[1];
    const float* be     = (const float*)d_in[2];
    const float* Wg     = (const float*)d_in[3];
    const float* bg     = (const float*)d_in[4];
    const float* eps_g  = (const float*)d_in[5];
    const float* gam    = (const float*)d_in[6];
    const float* bet    = (const float*)d_in[7];
    const float* Wp     = (const float*)d_in[8];
    const float* bp     = (const float*)d_in[9];
    const int* ori_node = (const int*)d_in[10];
    const int* node2edge= (const int*)d_in[11];
    const int* eiN      = (const int*)d_in[12];
    const int* ori_edge = (const int*)d_in[13];
    const int* edge2node= (const int*)d_in[14];
    const int* eiE      = (const int*)d_in[15];
    const int* batch    = (const int*)d_in[16];

    char* p = (char*)d_ws;
    auto take = [&](size_t n) { char* r = p; p += (n + 255) & ~(size_t)255; return r; };
    unsigned short* Wt  = (unsigned short*)take((size_t)17 * 16384 * 2);
    unsigned short* Xb  = (unsigned short*)take((size_t)M_COPIES * 128 * 2);
    unsigned short* Xb2 = (unsigned short*)take((size_t)M_COPIES * 128 * 2);
    unsigned short* nx  = (unsigned short*)take((size_t)N_NODES * 128 * 2);
    unsigned short* ex  = (unsigned short*)take((size_t)N_EDGES * 128 * 2);
    float* y            = (float*)take((size_t)N_NODES * NCLS * 4);
    float* score        = (float*)take((size_t)NBATCH * NCLS * 4);
    int* offN           = (int*)take((size_t)M_COPIES * 4);
    int* offE           = (int*)take((size_t)M_COPIES * 4);
    int* off_n2e        = (int*)take((size_t)N_EDGES * 4);
    int* off_e2n        = (int*)take((size_t)N_NODES * 4);
    int* srcsN          = (int*)take((size_t)L_EDGES * 4);
    int* compsN         = (int*)take((size_t)L_EDGES * 4);
    int* srcsE          = (int*)take((size_t)L_EDGES * 4);
    int* compsE         = (int*)take((size_t)L_EDGES * 4);
    int* it_n2e         = (int*)take((size_t)M_COPIES * 4);
    int* it_e2n         = (int*)take((size_t)M_COPIES * 4);
    int* part           = (int*)take((size_t)2048 * 4);
    size_t need = (size_t)(p - (char*)d_ws);
    if (need > ws_size) {
        fill_sentinel<<<(out_size + 63) / 64, 64, 0, stream>>>(
            (float*)d_out, out_size, 1.0e9f + (float)ws_size);
        return;
    }

    prep_w<<<1088, 256, 0, stream>>>(We, Wg, Wt);
    (void)hipMemsetAsync(score, 0, (size_t)NBATCH * NCLS * 4, stream);

    build_csr_edge(eiN, eiN + L_EDGES, ori_node, L_EDGES, M_COPIES, offN, part, srcsN, compsN, stream);
    build_csr_edge(eiE, eiE + L_EDGES, ori_edge, L_EDGES, M_COPIES, offE, part, srcsE, compsE, stream);
    build_csr_pool(node2edge, M_COPIES, N_EDGES, off_n2e, part, it_n2e, stream);
    build_csr_pool(edge2node, M_COPIES, N_NODES, off_e2n, part, it_e2n, stream);

    gemm_embed<<<(N_NODES + 63) / 64, 256, 0, stream>>>(x_N, Wt, be, nx, N_NODES);
    proj_y<false><<<(N_NODES + 255) / 256, 256, 0, stream>>>(nx, Wp, y, N_NODES);

    const int MBLK = M_COPIES / 64;   // 6250
    for (int layer = 0; layer < 2; ++layer) {
        for (int dir = 0; dir < 2; ++dir) {
            int cj0 = layer * 4 + dir * 2;
            int cj1 = cj0 + 1;
            const unsigned short* base = (dir == 0) ? nx : ex;
            const int* selfI = (dir == 0) ? ori_node : ori_edge;
            const int* offD  = (dir == 0) ? offN : offE;
            const int* srcsD = (dir == 0) ? srcsN : srcsE;
            const int* compD = (dir == 0) ? compsN : compsE;

            fused_conv<true><<<MBLK, 256, 0, stream>>>(
                base, selfI, offD, compD, eps_g + cj0,
                Wt + (size_t)(1 + cj0 * 2) * 16384, bg + (cj0 * 2) * 128,
                Wt + (size_t)(1 + cj0 * 2 + 1) * 16384, bg + (cj0 * 2 + 1) * 128,
                gam + cj0 * 128, bet + cj0 * 128, Xb);
            fused_conv<false><<<MBLK, 256, 0, stream>>>(
                Xb, nullptr, offD, srcsD, eps_g + cj1,
                Wt + (size_t)(1 + cj1 * 2) * 16384, bg + (cj1 * 2) * 128,
                Wt + (size_t)(1 + cj1 * 2 + 1) * 16384, bg + (cj1 * 2 + 1) * 128,
                gam + cj1 * 128, bet + cj1 * 128, Xb2);
            if (dir == 0) {
                segsum_pool<<<(N_EDGES + 15) / 16, 256, 0, stream>>>(
                    (const unsigned*)Xb2, off_n2e, it_n2e, (unsigned*)ex, N_EDGES);
            } else {
                segsum_pool<<<(N_NODES + 15) / 16, 256, 0, stream>>>(
                    (const unsigned*)Xb2, off_e2n, it_e2n, (unsigned*)nx, N_NODES);
                proj_y<true><<<(N_NODES + 255) / 256, 256, 0, stream>>>(
                    nx, Wp + (layer + 1) * HID * NCLS, y, N_NODES);
            }
        }
    }
    score_scatter<<<256, 256, 0, stream>>>(y, ori_node, batch, score);
    score_final<<<1, 320, 0, stream>>>(score, bp, (float*)d_out);
}

// Round 10
// 1956.929 us; speedup vs baseline: 1.0660x; 1.0660x over previous
//
#include <hip/hip_runtime.h>
#include <hip/hip_bf16.h>

// ---------------- problem constants ----------------
#define HID 128
static const int N_NODES = 50000;
static const int N_EDGES = 20000;
static const int M_COPIES = 400000;
static const int L_EDGES = 800000;
static const int NBATCH = 32;
static const int NCLS = 10;
#define INV_STD 0.9999950000374997f   // 1/sqrt(1+1e-5)

typedef __attribute__((ext_vector_type(4))) float f32x4;
typedef __attribute__((ext_vector_type(8))) short short8;      // 8 bf16 lanes
typedef __attribute__((ext_vector_type(8))) unsigned short ushort8;
typedef __attribute__((ext_vector_type(4))) unsigned short u16x4;  // 'ushort4' collides with HIP header

__device__ __forceinline__ float bf2f(unsigned short u) {
    union { unsigned u; float f; } v; v.u = ((unsigned)u) << 16; return v.f;
}
__device__ __forceinline__ unsigned short f2bf(float f) {
    union { float f; unsigned u; } v; v.f = f;
    unsigned r = v.u + 0x7FFFu + ((v.u >> 16) & 1u);   // RNE
    return (unsigned short)(r >> 16);
}
__device__ __forceinline__ void gatomic_add(float* p, float v) {
    unsafeAtomicAdd(p, v);
}

// ---------------- weight prep: Wt[mat][n][k] = bf16(W[mat][k][n]) ----------------
__global__ __launch_bounds__(256) void prep_w(const float* __restrict__ We,
                                              const float* __restrict__ Wg,
                                              unsigned short* __restrict__ Wt) {
    int t = blockIdx.x * 256 + threadIdx.x;       // 17*16384
    if (t >= 17 * 16384) return;
    int mat = t >> 14, rem = t & 16383;
    int n = rem >> 7, k = rem & 127;
    const float* src = (mat == 0) ? We : (Wg + (size_t)(mat - 1) * 16384);
    Wt[t] = f2bf(src[k * 128 + n]);
}

// ---------------- CSR build ----------------
__global__ __launch_bounds__(256) void hist_k(const int* __restrict__ idx, int n,
                                              int* __restrict__ cnt) {
    int t = blockIdx.x * 256 + threadIdx.x;
    if (t < n) atomicAdd(&cnt[idx[t]], 1);
}

__global__ __launch_bounds__(256) void scan1_k(int* __restrict__ a, int n,
                                               int* __restrict__ part) {
    __shared__ int s[256];
    int i = blockIdx.x * 256 + threadIdx.x;
    int v = (i < n) ? a[i] : 0;
    s[threadIdx.x] = v;
    __syncthreads();
#pragma unroll
    for (int d = 1; d < 256; d <<= 1) {
        int t = (threadIdx.x >= d) ? s[threadIdx.x - d] : 0;
        __syncthreads();
        s[threadIdx.x] += t;
        __syncthreads();
    }
    if (i < n) a[i] = s[threadIdx.x] - v;
    if (threadIdx.x == 255) part[blockIdx.x] = s[255];
}

__global__ __launch_bounds__(256) void scan2_k(int* __restrict__ part, int nb) {
    __shared__ int s[256];
    __shared__ int carry;
    if (threadIdx.x == 0) carry = 0;
    __syncthreads();
    for (int base = 0; base < nb; base += 256) {
        int i = base + threadIdx.x;
        int v = (i < nb) ? part[i] : 0;
        s[threadIdx.x] = v;
        __syncthreads();
#pragma unroll
        for (int d = 1; d < 256; d <<= 1) {
            int t = (threadIdx.x >= d) ? s[threadIdx.x - d] : 0;
            __syncthreads();
            s[threadIdx.x] += t;
            __syncthreads();
        }
        if (i < nb) part[i] = carry + s[threadIdx.x] - v;
        __syncthreads();
        if (threadIdx.x == 0) carry += s[255];
        __syncthreads();
    }
}

__global__ __launch_bounds__(256) void scan3_k(int* __restrict__ a, int n,
                                               const int* __restrict__ part) {
    int i = blockIdx.x * 256 + threadIdx.x;
    if (i < n) a[i] += part[blockIdx.x];
}

__global__ __launch_bounds__(256) void fill_edge_k(
    const int* __restrict__ src, const int* __restrict__ dst,
    const int* __restrict__ remap, int n, int* __restrict__ off,
    int* __restrict__ srcs, int* __restrict__ comps) {
    int e = blockIdx.x * 256 + threadIdx.x;
    if (e >= n) return;
    int d = dst[e];
    int pos = atomicAdd(&off[d], 1);
    int s = src[e];
    srcs[pos] = s;
    comps[pos] = remap[s];
}

__global__ __launch_bounds__(256) void fill_pool_k(
    const int* __restrict__ seg, int n, int* __restrict__ off,
    int* __restrict__ items) {
    int m = blockIdx.x * 256 + threadIdx.x;
    if (m >= n) return;
    int pos = atomicAdd(&off[seg[m]], 1);
    items[pos] = m;
}

// ---------------- pool segment sum: out[m]=relu(sum tbl[items]); 4 segs/wave ----------------
__global__ __launch_bounds__(256) void segsum_pool(
    const unsigned* __restrict__ tbl, const int* __restrict__ off,
    const int* __restrict__ items, unsigned* __restrict__ out, int nseg)
{
    int wave = threadIdx.x >> 6, lane = threadIdx.x & 63;
    int mb = blockIdx.x * 16 + wave * 4;
    float a0[4] = {0.f, 0.f, 0.f, 0.f}, a1[4] = {0.f, 0.f, 0.f, 0.f};
    int pos[4], end[4];
#pragma unroll
    for (int i = 0; i < 4; ++i) {
        int m = mb + i;
        if (m < nseg) { pos[i] = (m == 0) ? 0 : off[m - 1]; end[i] = off[m]; }
        else { pos[i] = 0; end[i] = 0; }
    }
    bool more = (pos[0] < end[0]) | (pos[1] < end[1]) | (pos[2] < end[2]) | (pos[3] < end[3]);
    while (more) {
        more = false;
        unsigned v[4]; bool ld[4];
#pragma unroll
        for (int i = 0; i < 4; ++i) {
            ld[i] = pos[i] < end[i];
            if (ld[i]) v[i] = tbl[(size_t)items[pos[i]] * 64 + lane];
        }
#pragma unroll
        for (int i = 0; i < 4; ++i) if (ld[i]) {
            a0[i] += bf2f((unsigned short)(v[i] & 0xffffu));
            a1[i] += bf2f((unsigned short)(v[i] >> 16));
            ++pos[i];
            more = more || (pos[i] < end[i]);
        }
    }
#pragma unroll
    for (int i = 0; i < 4; ++i) {
        int m = mb + i;
        if (m < nseg) {
            float r0 = fmaxf(a0[i], 0.f), r1 = fmaxf(a1[i], 0.f);
            out[(size_t)m * 64 + lane] = (unsigned)f2bf(r0) | ((unsigned)f2bf(r1) << 16);
        }
    }
}

// ---------------- fused GIN conv: 512 threads / 128 rows per block ----------------
// segsum-gather (sequential per-row walk) + linear1+ReLU + linear2+BN(+ReLU).
// Operand-swapped MFMAs: lane holds out[row][4 consecutive channels] -> 8B stores.
// CONV0: self = self_idx[m], items = comps; final ReLU. !CONV0: self = m, items = srcs.
template<bool CONV0>
__global__ __launch_bounds__(512) void fused_conv(
    const unsigned short* __restrict__ tbl,
    const int* __restrict__ self_idx,
    const int* __restrict__ off, const int* __restrict__ items,
    const float* __restrict__ eps_ptr,
    const unsigned short* __restrict__ W1t, const float* __restrict__ b1,
    const unsigned short* __restrict__ W2t, const float* __restrict__ b2,
    const float* __restrict__ gam, const float* __restrict__ bet,
    unsigned short* __restrict__ out)
{
    __shared__ __align__(16) unsigned short Xs[16 * 128 * 8];  // 32 KB: [chunk][row][8]
    __shared__ __align__(16) unsigned short Ws[16 * 128 * 8];  // 32 KB
    __shared__ int meta[384];
    const int tid = threadIdx.x;
    const int row0 = blockIdx.x * 128;

    if (tid < 128) {
        int gr = row0 + tid;
        meta[tid]        = (gr == 0) ? 0 : off[gr - 1];
        meta[128 + tid]  = off[gr];
        meta[256 + tid]  = CONV0 ? self_idx[gr] : gr;
    }
    // stage W1: 2048 chunks of 16B by 512 threads
#pragma unroll
    for (int i = 0; i < 4; ++i) {
        int chunk = tid + i * 512;
        int n = chunk >> 4, gg = chunk & 15;
        *(short8*)(Ws + (gg * 128 + n) * 8) = *(const short8*)(W1t + n * 128 + gg * 8);
    }
    __syncthreads();

    // ---- gather: thread (rb,g) walks rows rb+32i sequentially (16 lanes co-read a row) ----
    const float e = 1.0f + eps_ptr[0];
    const int g = tid & 15;
    const int rb = tid >> 4;        // 0..31
#pragma unroll
    for (int i = 0; i < 4; ++i) {
        int r = rb + 32 * i;
        int start = meta[r], end = meta[128 + r], self = meta[256 + r];
        float a[8];
        ushort8 u = *(const ushort8*)(tbl + (size_t)self * 128 + g * 8);
#pragma unroll
        for (int j = 0; j < 8; ++j) a[j] = e * bf2f(u[j]);
        for (int pos = start; pos < end; ++pos) {
            int rr = items[pos];
            ushort8 v = *(const ushort8*)(tbl + (size_t)rr * 128 + g * 8);
#pragma unroll
            for (int j = 0; j < 8; ++j) a[j] += bf2f(v[j]);
        }
        ushort8 xv;
#pragma unroll
        for (int j = 0; j < 8; ++j) xv[j] = f2bf(a[j]);
        *(ushort8*)(Xs + (g * 128 + r) * 8) = xv;
    }
    __syncthreads();

    const int wave = tid >> 6, lane = tid & 63;
    const int ln = lane & 15, quad = lane >> 4;
    const int row = wave * 16 + ln;     // wave-private X/H row (8 waves x 16 rows = 128)

    // ---- MFMA 1 (swapped): lane holds H[row][p0..p0+3] ----
    f32x4 acc[8];
#pragma unroll
    for (int t = 0; t < 8; ++t) acc[t] = (f32x4){0.f, 0.f, 0.f, 0.f};
#pragma unroll
    for (int kc = 0; kc < 4; ++kc) {
        int gl = kc * 4 + quad;
        short8 xb = *(const short8*)(Xs + (gl * 128 + row) * 8);
#pragma unroll
        for (int t = 0; t < 8; ++t) {
            short8 wa = *(const short8*)(Ws + (gl * 128 + t * 16 + ln) * 8);
            acc[t] = __builtin_amdgcn_mfma_f32_16x16x32_bf16(wa, xb, acc[t], 0, 0, 0);
        }
    }
    // h = relu(acc + b1) -> Xs[H[row][p]], 4 consecutive channels per reg -> 8B writes
    {
        const int j0 = (quad & 1) * 4;
#pragma unroll
        for (int t = 0; t < 8; ++t) {
            int p0 = t * 16 + quad * 4;
            f32x4 bv = *(const f32x4*)(b1 + p0);
            u16x4 hp;
#pragma unroll
            for (int i = 0; i < 4; ++i) hp[i] = f2bf(fmaxf(acc[t][i] + bv[i], 0.f));
            *(u16x4*)(Xs + ((p0 >> 3) * 128 + row) * 8 + j0) = hp;
        }
    }
    __syncthreads();
    // stage W2
#pragma unroll
    for (int i = 0; i < 4; ++i) {
        int chunk = tid + i * 512;
        int n = chunk >> 4, gg = chunk & 15;
        *(short8*)(Ws + (gg * 128 + n) * 8) = *(const short8*)(W2t + n * 128 + gg * 8);
    }
    __syncthreads();

    // ---- MFMA 2 (swapped): lane holds out[row0+row][n0..n0+3] ----
#pragma unroll
    for (int t = 0; t < 8; ++t) acc[t] = (f32x4){0.f, 0.f, 0.f, 0.f};
#pragma unroll
    for (int kc = 0; kc < 4; ++kc) {
        int gl = kc * 4 + quad;
        short8 hb = *(const short8*)(Xs + (gl * 128 + row) * 8);
#pragma unroll
        for (int t = 0; t < 8; ++t) {
            short8 wa = *(const short8*)(Ws + (gl * 128 + t * 16 + ln) * 8);
            acc[t] = __builtin_amdgcn_mfma_f32_16x16x32_bf16(wa, hb, acc[t], 0, 0, 0);
        }
    }
    const int m = row0 + row;
#pragma unroll
    for (int t = 0; t < 8; ++t) {
        int n0 = t * 16 + quad * 4;
        f32x4 bv = *(const f32x4*)(b2 + n0);
        f32x4 gv = *(const f32x4*)(gam + n0);
        f32x4 tv = *(const f32x4*)(bet + n0);
        u16x4 op;
#pragma unroll
        for (int i = 0; i < 4; ++i) {
            float h = acc[t][i] + bv[i];
            h = gv[i] * h * INV_STD + tv[i];
            if (CONV0) h = fmaxf(h, 0.f);
            op[i] = f2bf(h);
        }
        *(u16x4*)(out + (size_t)m * 128 + n0) = op;
    }
}

// ---------------- embedding GEMM (f32 in): out = in @ W + b ----------------
__global__ __launch_bounds__(256) void gemm_embed(
    const float* __restrict__ in, const unsigned short* __restrict__ Wt,
    const float* __restrict__ bias, unsigned short* __restrict__ out_bf, int rows)
{
    __shared__ __align__(16) unsigned short Xs[16 * 64 * 8];
    __shared__ __align__(16) unsigned short Ws[16 * 128 * 8];
    int tid = threadIdx.x;
    int row0 = blockIdx.x * 64;
#pragma unroll
    for (int i = 0; i < 8; ++i) {
        int chunk = tid + i * 256;
        int n = chunk >> 4, g = chunk & 15;
        *(short8*)(Ws + (g * 128 + n) * 8) = *(const short8*)(Wt + n * 128 + g * 8);
    }
#pragma unroll
    for (int i = 0; i < 4; ++i) {
        int chunk = tid + i * 256;
        int r = chunk >> 4, g = chunk & 15;
        int gr = row0 + r;
        ushort8 v;
        if (gr < rows) {
            const float* p = in + (size_t)gr * 128 + g * 8;
            f32x4 a0 = *(const f32x4*)p;
            f32x4 a1 = *(const f32x4*)(p + 4);
#pragma unroll
            for (int j = 0; j < 4; ++j) { v[j] = f2bf(a0[j]); v[4 + j] = f2bf(a1[j]); }
        } else {
#pragma unroll
            for (int j = 0; j < 8; ++j) v[j] = 0;
        }
        *(ushort8*)(Xs + (g * 64 + r) * 8) = v;
    }
    __syncthreads();
    int wave = tid >> 6, lane = tid & 63;
    int m0 = wave * 16;
    int ln = lane & 15, quad = lane >> 4;
    f32x4 acc[8];
#pragma unroll
    for (int t = 0; t < 8; ++t) acc[t] = (f32x4){0.f, 0.f, 0.f, 0.f};
#pragma unroll
    for (int kc = 0; kc < 4; ++kc) {
        int g = kc * 4 + quad;
        short8 a = *(const short8*)(Xs + (g * 64 + m0 + ln) * 8);
#pragma unroll
        for (int t = 0; t < 8; ++t) {
            short8 b = *(const short8*)(Ws + (g * 128 + t * 16 + ln) * 8);
            acc[t] = __builtin_amdgcn_mfma_f32_16x16x32_bf16(a, b, acc[t], 0, 0, 0);
        }
    }
#pragma unroll
    for (int t = 0; t < 8; ++t) {
        int col = t * 16 + ln;
        float bi = bias[col];
#pragma unroll
        for (int i = 0; i < 4; ++i) {
            int gr = row0 + m0 + quad * 4 + i;
            if (gr < rows) out_bf[(size_t)gr * 128 + col] = f2bf(acc[t][i] + bi);
        }
    }
}

// ---------------- y projection: y[r][10] (+)= nx[r][:] @ Wp ----------------
template<bool ACCUM>
__global__ __launch_bounds__(256) void proj_y(
    const unsigned short* __restrict__ nx, const float* __restrict__ Wp,
    float* __restrict__ y, int rows)
{
    __shared__ float Wl[HID * NCLS];
    for (int i = threadIdx.x; i < HID * NCLS; i += 256) Wl[i] = Wp[i];
    __syncthreads();
    int r = blockIdx.x * 256 + threadIdx.x;
    if (r >= rows) return;
    float acc[NCLS];
#pragma unroll
    for (int c = 0; c < NCLS; ++c) acc[c] = 0.f;
    const unsigned short* xp = nx + (size_t)r * 128;
#pragma unroll 4
    for (int g = 0; g < 16; ++g) {
        ushort8 u = *(const ushort8*)(xp + g * 8);
#pragma unroll
        for (int j = 0; j < 8; ++j) {
            float xv = bf2f(u[j]);
            const float* w = Wl + (g * 8 + j) * NCLS;
#pragma unroll
            for (int c = 0; c < NCLS; ++c) acc[c] += xv * w[c];
        }
    }
    float* yp = y + (size_t)r * NCLS;
#pragma unroll
    for (int c = 0; c < NCLS; ++c) {
        if (ACCUM) yp[c] += acc[c];
        else yp[c] = acc[c];
    }
}

// ---------------- score scatter: score[b][:] += y[ori[m]][:] ----------------
__global__ __launch_bounds__(256) void score_scatter(
    const float* __restrict__ y, const int* __restrict__ ori,
    const int* __restrict__ batch, float* __restrict__ score)
{
    __shared__ float sc[NBATCH * NCLS];
    for (int i = threadIdx.x; i < NBATCH * NCLS; i += 256) sc[i] = 0.f;
    __syncthreads();
    int stride = gridDim.x * 256;
    for (int m = blockIdx.x * 256 + threadIdx.x; m < M_COPIES; m += stride) {
        int r = ori[m], b = batch[m];
        const float* yp = y + (size_t)r * NCLS;
#pragma unroll
        for (int c = 0; c < NCLS; ++c)
            __hip_atomic_fetch_add(&sc[b * NCLS + c], yp[c],
                                   __ATOMIC_RELAXED, __HIP_MEMORY_SCOPE_WORKGROUP);
    }
    __syncthreads();
    for (int i = threadIdx.x; i < NBATCH * NCLS; i += 256) gatomic_add(score + i, sc[i]);
}

__global__ void score_final(const float* __restrict__ score, const float* __restrict__ bp,
                            float* __restrict__ out)
{
    int t = threadIdx.x;
    if (t >= NBATCH * NCLS) return;
    int c = t % NCLS;
    out[t] = score[t] + bp[c] + bp[NCLS + c] + bp[2 * NCLS + c];
}

__global__ void fill_sentinel(float* out, int n, float enc) {
    int t = blockIdx.x * 64 + threadIdx.x;
    if (t < n) out[t] = enc;
}

// ---------------- helpers ----------------
static inline void build_csr_edge(const int* src, const int* dst, const int* remap,
                                  int nitem, int nseg, int* off, int* part,
                                  int* srcs, int* comps, hipStream_t stream) {
    int nb = (nseg + 255) / 256;
    (void)hipMemsetAsync(off, 0, (size_t)nseg * 4, stream);
    hist_k<<<(nitem + 255) / 256, 256, 0, stream>>>(dst, nitem, off);
    scan1_k<<<nb, 256, 0, stream>>>(off, nseg, part);
    scan2_k<<<1, 256, 0, stream>>>(part, nb);
    scan3_k<<<nb, 256, 0, stream>>>(off, nseg, part);
    fill_edge_k<<<(nitem + 255) / 256, 256, 0, stream>>>(src, dst, remap, nitem, off, srcs, comps);
}
static inline void build_csr_pool(const int* seg, int nitem, int nseg,
                                  int* off, int* part, int* items, hipStream_t stream) {
    int nb = (nseg + 255) / 256;
    (void)hipMemsetAsync(off, 0, (size_t)nseg * 4, stream);
    hist_k<<<(nitem + 255) / 256, 256, 0, stream>>>(seg, nitem, off);
    scan1_k<<<nb, 256, 0, stream>>>(off, nseg, part);
    scan2_k<<<1, 256, 0, stream>>>(part, nb);
    scan3_k<<<nb, 256, 0, stream>>>(off, nseg, part);
    fill_pool_k<<<(nitem + 255) / 256, 256, 0, stream>>>(seg, nitem, off, items);
}

// ---------------- entry ----------------
extern "C" void kernel_launch(void* const* d_in, const int* in_sizes, int n_in,
                              void* d_out, int out_size, void* d_ws, size_t ws_size,
                              hipStream_t stream) {
    const float* x_N    = (const float*)d_in[0];
    const float* We     = (const float*)d_in[1];
    const float* be     = (const float*)d_in[2];
    const float* Wg     = (const float*)d_in[3];
    const float* bg     = (const float*)d_in[4];
    const float* eps_g  = (const float*)d_in[5];
    const float* gam    = (const float*)d_in[6];
    const float* bet    = (const float*)d_in[7];
    const float* Wp     = (const float*)d_in[8];
    const float* bp     = (const float*)d_in[9];
    const int* ori_node = (const int*)d_in[10];
    const int* node2edge= (const int*)d_in[11];
    const int* eiN      = (const int*)d_in[12];
    const int* ori_edge = (const int*)d_in[13];
    const int* edge2node= (const int*)d_in[14];
    const int* eiE      = (const int*)d_in[15];
    const int* batch    = (const int*)d_in[16];

    char* p = (char*)d_ws;
    auto take = [&](size_t n) { char* r = p; p += (n + 255) & ~(size_t)255; return r; };
    unsigned short* Wt  = (unsigned short*)take((size_t)17 * 16384 * 2);
    unsigned short* Xb  = (unsigned short*)take((size_t)M_COPIES * 128 * 2);
    unsigned short* Xb2 = (unsigned short*)take((size_t)M_COPIES * 128 * 2);
    unsigned short* nx  = (unsigned short*)take((size_t)N_NODES * 128 * 2);
    unsigned short* ex  = (unsigned short*)take((size_t)N_EDGES * 128 * 2);
    float* y            = (float*)take((size_t)N_NODES * NCLS * 4);
    float* score        = (float*)take((size_t)NBATCH * NCLS * 4);
    int* offN           = (int*)take((size_t)M_COPIES * 4);
    int* offE           = (int*)take((size_t)M_COPIES * 4);
    int* off_n2e        = (int*)take((size_t)N_EDGES * 4);
    int* off_e2n        = (int*)take((size_t)N_NODES * 4);
    int* srcsN          = (int*)take((size_t)L_EDGES * 4);
    int* compsN         = (int*)take((size_t)L_EDGES * 4);
    int* srcsE          = (int*)take((size_t)L_EDGES * 4);
    int* compsE         = (int*)take((size_t)L_EDGES * 4);
    int* it_n2e         = (int*)take((size_t)M_COPIES * 4);
    int* it_e2n         = (int*)take((size_t)M_COPIES * 4);
    int* part           = (int*)take((size_t)2048 * 4);
    size_t need = (size_t)(p - (char*)d_ws);
    if (need > ws_size) {
        fill_sentinel<<<(out_size + 63) / 64, 64, 0, stream>>>(
            (float*)d_out, out_size, 1.0e9f + (float)ws_size);
        return;
    }

    prep_w<<<1088, 256, 0, stream>>>(We, Wg, Wt);
    (void)hipMemsetAsync(score, 0, (size_t)NBATCH * NCLS * 4, stream);

    build_csr_edge(eiN, eiN + L_EDGES, ori_node, L_EDGES, M_COPIES, offN, part, srcsN, compsN, stream);
    build_csr_edge(eiE, eiE + L_EDGES, ori_edge, L_EDGES, M_COPIES, offE, part, srcsE, compsE, stream);
    build_csr_pool(node2edge, M_COPIES, N_EDGES, off_n2e, part, it_n2e, stream);
    build_csr_pool(edge2node, M_COPIES, N_NODES, off_e2n, part, it_e2n, stream);

    gemm_embed<<<(N_NODES + 63) / 64, 256, 0, stream>>>(x_N, Wt, be, nx, N_NODES);
    proj_y<false><<<(N_NODES + 255) / 256, 256, 0, stream>>>(nx, Wp, y, N_NODES);

    const int MBLK = M_COPIES / 128;   // 3125 blocks of 512 threads
    for (int layer = 0; layer < 2; ++layer) {
        for (int dir = 0; dir < 2; ++dir) {
            int cj0 = layer * 4 + dir * 2;
            int cj1 = cj0 + 1;
            const unsigned short* base = (dir == 0) ? nx : ex;
            const int* selfI = (dir == 0) ? ori_node : ori_edge;
            const int* offD  = (dir == 0) ? offN : offE;
            const int* srcsD = (dir == 0) ? srcsN : srcsE;
            const int* compD = (dir == 0) ? compsN : compsE;

            fused_conv<true><<<MBLK, 512, 0, stream>>>(
                base, selfI, offD, compD, eps_g + cj0,
                Wt + (size_t)(1 + cj0 * 2) * 16384, bg + (cj0 * 2) * 128,
                Wt + (size_t)(1 + cj0 * 2 + 1) * 16384, bg + (cj0 * 2 + 1) * 128,
                gam + cj0 * 128, bet + cj0 * 128, Xb);
            fused_conv<false><<<MBLK, 512, 0, stream>>>(
                Xb, nullptr, offD, srcsD, eps_g + cj1,
                Wt + (size_t)(1 + cj1 * 2) * 16384, bg + (cj1 * 2) * 128,
                Wt + (size_t)(1 + cj1 * 2 + 1) * 16384, bg + (cj1 * 2 + 1) * 128,
                gam + cj1 * 128, bet + cj1 * 128, Xb2);
            if (dir == 0) {
                segsum_pool<<<(N_EDGES + 15) / 16, 256, 0, stream>>>(
                    (const unsigned*)Xb2, off_n2e, it_n2e, (unsigned*)ex, N_EDGES);
            } else {
                segsum_pool<<<(N_NODES + 15) / 16, 256, 0, stream>>>(
                    (const unsigned*)Xb2, off_e2n, it_e2n, (unsigned*)nx, N_NODES);
                proj_y<true><<<(N_NODES + 255) / 256, 256, 0, stream>>>(
                    nx, Wp + (layer + 1) * HID * NCLS, y, N_NODES);
            }
        }
    }
    score_scatter<<<256, 256, 0, stream>>>(y, ori_node, batch, score);
    score_final<<<1, 320, 0, stream>>>(score, bp, (float*)d_out);
}

// Round 11
// 1854.859 us; speedup vs baseline: 1.1246x; 1.0550x over previous
//
#include <hip/hip_runtime.h>
#include <hip/hip_bf16.h>

// ---------------- problem constants ----------------
#define HID 128
static const int N_NODES = 50000;
static const int N_EDGES = 20000;
static const int M_COPIES = 400000;
static const int L_EDGES = 800000;
static const int NBATCH = 32;
static const int NCLS = 10;
#define INV_STD 0.9999950000374997f   // 1/sqrt(1+1e-5)
#define IDX_CAP 768                   // fused_conv per-block item cap (avg 128)
#define POOL_CAP 2048                 // segsum_pool per-block item cap (avg <=320)

typedef __attribute__((ext_vector_type(4))) float f32x4;
typedef __attribute__((ext_vector_type(8))) short short8;      // 8 bf16 lanes
typedef __attribute__((ext_vector_type(8))) unsigned short ushort8;
typedef __attribute__((ext_vector_type(4))) unsigned short u16x4;  // 'ushort4' collides with HIP header

__device__ __forceinline__ float bf2f(unsigned short u) {
    union { unsigned u; float f; } v; v.u = ((unsigned)u) << 16; return v.f;
}
__device__ __forceinline__ unsigned short f2bf(float f) {
    union { float f; unsigned u; } v; v.f = f;
    unsigned r = v.u + 0x7FFFu + ((v.u >> 16) & 1u);   // RNE
    return (unsigned short)(r >> 16);
}
__device__ __forceinline__ void gatomic_add(float* p, float v) {
    unsafeAtomicAdd(p, v);
}

// ---------------- weight prep: Wt[mat][n][k] = bf16(W[mat][k][n]) ----------------
__global__ __launch_bounds__(256) void prep_w(const float* __restrict__ We,
                                              const float* __restrict__ Wg,
                                              unsigned short* __restrict__ Wt) {
    int t = blockIdx.x * 256 + threadIdx.x;       // 17*16384
    if (t >= 17 * 16384) return;
    int mat = t >> 14, rem = t & 16383;
    int n = rem >> 7, k = rem & 127;
    const float* src = (mat == 0) ? We : (Wg + (size_t)(mat - 1) * 16384);
    Wt[t] = f2bf(src[k * 128 + n]);
}

// ---------------- CSR build ----------------
__global__ __launch_bounds__(256) void hist_k(const int* __restrict__ idx, int n,
                                              int* __restrict__ cnt) {
    int t = blockIdx.x * 256 + threadIdx.x;
    if (t < n) atomicAdd(&cnt[idx[t]], 1);
}

__global__ __launch_bounds__(256) void scan1_k(int* __restrict__ a, int n,
                                               int* __restrict__ part) {
    __shared__ int s[256];
    int i = blockIdx.x * 256 + threadIdx.x;
    int v = (i < n) ? a[i] : 0;
    s[threadIdx.x] = v;
    __syncthreads();
#pragma unroll
    for (int d = 1; d < 256; d <<= 1) {
        int t = (threadIdx.x >= d) ? s[threadIdx.x - d] : 0;
        __syncthreads();
        s[threadIdx.x] += t;
        __syncthreads();
    }
    if (i < n) a[i] = s[threadIdx.x] - v;
    if (threadIdx.x == 255) part[blockIdx.x] = s[255];
}

__global__ __launch_bounds__(256) void scan2_k(int* __restrict__ part, int nb) {
    __shared__ int s[256];
    __shared__ int carry;
    if (threadIdx.x == 0) carry = 0;
    __syncthreads();
    for (int base = 0; base < nb; base += 256) {
        int i = base + threadIdx.x;
        int v = (i < nb) ? part[i] : 0;
        s[threadIdx.x] = v;
        __syncthreads();
#pragma unroll
        for (int d = 1; d < 256; d <<= 1) {
            int t = (threadIdx.x >= d) ? s[threadIdx.x - d] : 0;
            __syncthreads();
            s[threadIdx.x] += t;
            __syncthreads();
        }
        if (i < nb) part[i] = carry + s[threadIdx.x] - v;
        __syncthreads();
        if (threadIdx.x == 0) carry += s[255];
        __syncthreads();
    }
}

__global__ __launch_bounds__(256) void scan3_k(int* __restrict__ a, int n,
                                               const int* __restrict__ part) {
    int i = blockIdx.x * 256 + threadIdx.x;
    if (i < n) a[i] += part[blockIdx.x];
}

__global__ __launch_bounds__(256) void fill_edge_k(
    const int* __restrict__ src, const int* __restrict__ dst,
    const int* __restrict__ remap, int n, int* __restrict__ off,
    int* __restrict__ srcs, int* __restrict__ comps) {
    int e = blockIdx.x * 256 + threadIdx.x;
    if (e >= n) return;
    int d = dst[e];
    int pos = atomicAdd(&off[d], 1);
    int s = src[e];
    srcs[pos] = s;
    comps[pos] = remap[s];
}

__global__ __launch_bounds__(256) void fill_pool_k(
    const int* __restrict__ seg, int n, int* __restrict__ off,
    int* __restrict__ items) {
    int m = blockIdx.x * 256 + threadIdx.x;
    if (m >= n) return;
    int pos = atomicAdd(&off[seg[m]], 1);
    items[pos] = m;
}

// ---------------- pool segment sum: out[m]=relu(sum tbl[items]); LDS-staged idx ----------------
__global__ __launch_bounds__(256) void segsum_pool(
    const unsigned* __restrict__ tbl, const int* __restrict__ off,
    const int* __restrict__ items, unsigned* __restrict__ out, int nseg)
{
    __shared__ int sIdx[POOL_CAP];
    int tid = threadIdx.x;
    int wave = tid >> 6, lane = tid & 63;
    int s0 = blockIdx.x * 16;
    int sN = min(s0 + 16, nseg);
    int bstart = (s0 == 0) ? 0 : off[s0 - 1];
    int bend = off[sN - 1];
    int cnt = bend - bstart;
    bool useLds = (cnt <= POOL_CAP);
    if (useLds)
        for (int i = tid; i < cnt; i += 256) sIdx[i] = items[bstart + i];
    __syncthreads();

    int mb = s0 + wave * 4;
    float a0[4] = {0.f, 0.f, 0.f, 0.f}, a1[4] = {0.f, 0.f, 0.f, 0.f};
    int pos[4], end[4];
#pragma unroll
    for (int i = 0; i < 4; ++i) {
        int m = mb + i;
        if (m < nseg) { pos[i] = (m == 0) ? 0 : off[m - 1]; end[i] = off[m]; }
        else { pos[i] = 0; end[i] = 0; }
    }
    bool more = (pos[0] < end[0]) | (pos[1] < end[1]) | (pos[2] < end[2]) | (pos[3] < end[3]);
    while (more) {
        more = false;
        unsigned v[4]; bool ld[4];
#pragma unroll
        for (int i = 0; i < 4; ++i) {
            ld[i] = pos[i] < end[i];
            if (ld[i]) {
                int r = useLds ? sIdx[pos[i] - bstart] : items[pos[i]];
                v[i] = tbl[(size_t)r * 64 + lane];
            }
        }
#pragma unroll
        for (int i = 0; i < 4; ++i) if (ld[i]) {
            a0[i] += bf2f((unsigned short)(v[i] & 0xffffu));
            a1[i] += bf2f((unsigned short)(v[i] >> 16));
            ++pos[i];
            more = more || (pos[i] < end[i]);
        }
    }
#pragma unroll
    for (int i = 0; i < 4; ++i) {
        int m = mb + i;
        if (m < nseg) {
            float r0 = fmaxf(a0[i], 0.f), r1 = fmaxf(a1[i], 0.f);
            out[(size_t)m * 64 + lane] = (unsigned)f2bf(r0) | ((unsigned)f2bf(r1) << 16);
        }
    }
}

// ---------------- fused GIN conv: 256 threads / 64 rows, LDS-staged idx ----------------
// gather-segsum + linear1+ReLU + linear2+BN(+ReLU). Operand-swapped MFMAs.
// CONV0: self = self_idx[m], items = comps; final ReLU. !CONV0: self = m, items = srcs.
template<bool CONV0>
__global__ __launch_bounds__(256) void fused_conv(
    const unsigned short* __restrict__ tbl,
    const int* __restrict__ self_idx,
    const int* __restrict__ off, const int* __restrict__ items,
    const float* __restrict__ eps_ptr,
    const unsigned short* __restrict__ W1t, const float* __restrict__ b1,
    const unsigned short* __restrict__ W2t, const float* __restrict__ b2,
    const float* __restrict__ gam, const float* __restrict__ bet,
    unsigned short* __restrict__ out)
{
    __shared__ __align__(16) unsigned short Xs[16 * 64 * 8];   // 16 KB: [chunk][row][8]
    __shared__ __align__(16) unsigned short Ws[16 * 128 * 8];  // 32 KB
    __shared__ int sIdx[IDX_CAP];                              // 3 KB
    __shared__ int meta[192];
    const int tid = threadIdx.x;
    const int row0 = blockIdx.x * 64;

    if (tid < 64) {
        int gr = row0 + tid;
        meta[tid]       = (gr == 0) ? 0 : off[gr - 1];
        meta[64 + tid]  = off[gr];
        meta[128 + tid] = CONV0 ? self_idx[gr] : gr;
    }
    __syncthreads();
    const int bstart = meta[0];
    const int cnt = meta[127] - bstart;
    const bool useLds = (cnt <= IDX_CAP);

    // stage W1 (2048 chunks of 16B) + item indices
#pragma unroll
    for (int i = 0; i < 8; ++i) {
        int chunk = tid + i * 256;
        int n = chunk >> 4, gg = chunk & 15;
        *(short8*)(Ws + (gg * 128 + n) * 8) = *(const short8*)(W1t + n * 128 + gg * 8);
    }
    if (useLds)
        for (int i = tid; i < cnt; i += 256) sIdx[i] = items[bstart + i];
    __syncthreads();

    // ---- gather: thread (rb,g) walks rows rb+16i; idx from LDS, 2-wide loads ----
    const float e = 1.0f + eps_ptr[0];
    const int g = tid & 15;
    const int rb = tid >> 4;        // 0..15
#pragma unroll
    for (int i = 0; i < 4; ++i) {
        int r = rb + 16 * i;
        int start = meta[r], end = meta[64 + r], self = meta[128 + r];
        float a[8];
        ushort8 u = *(const ushort8*)(tbl + (size_t)self * 128 + g * 8);
#pragma unroll
        for (int j = 0; j < 8; ++j) a[j] = e * bf2f(u[j]);
        if (useLds) {
            int pos = start - bstart, pe = end - bstart;
            for (; pos + 2 <= pe; pos += 2) {
                int i0 = sIdx[pos], i1 = sIdx[pos + 1];
                ushort8 v0 = *(const ushort8*)(tbl + (size_t)i0 * 128 + g * 8);
                ushort8 v1 = *(const ushort8*)(tbl + (size_t)i1 * 128 + g * 8);
#pragma unroll
                for (int j = 0; j < 8; ++j) a[j] += bf2f(v0[j]) + bf2f(v1[j]);
            }
            if (pos < pe) {
                int i0 = sIdx[pos];
                ushort8 v0 = *(const ushort8*)(tbl + (size_t)i0 * 128 + g * 8);
#pragma unroll
                for (int j = 0; j < 8; ++j) a[j] += bf2f(v0[j]);
            }
        } else {
            for (int pos = start; pos < end; ++pos) {
                int rr = items[pos];
                ushort8 v = *(const ushort8*)(tbl + (size_t)rr * 128 + g * 8);
#pragma unroll
                for (int j = 0; j < 8; ++j) a[j] += bf2f(v[j]);
            }
        }
        ushort8 xv;
#pragma unroll
        for (int j = 0; j < 8; ++j) xv[j] = f2bf(a[j]);
        *(ushort8*)(Xs + (g * 64 + r) * 8) = xv;
    }
    __syncthreads();

    const int wave = tid >> 6, lane = tid & 63;
    const int ln = lane & 15, quad = lane >> 4;
    const int row = wave * 16 + ln;     // wave-private X/H row (4 waves x 16 = 64)

    // ---- MFMA 1 (swapped): lane holds H[row][p0..p0+3] ----
    f32x4 acc[8];
#pragma unroll
    for (int t = 0; t < 8; ++t) acc[t] = (f32x4){0.f, 0.f, 0.f, 0.f};
#pragma unroll
    for (int kc = 0; kc < 4; ++kc) {
        int gl = kc * 4 + quad;
        short8 xb = *(const short8*)(Xs + (gl * 64 + row) * 8);
#pragma unroll
        for (int t = 0; t < 8; ++t) {
            short8 wa = *(const short8*)(Ws + (gl * 128 + t * 16 + ln) * 8);
            acc[t] = __builtin_amdgcn_mfma_f32_16x16x32_bf16(wa, xb, acc[t], 0, 0, 0);
        }
    }
    // h = relu(acc + b1) -> Xs[H[row][p]], 4 consecutive channels -> 8B writes
    {
        const int j0 = (quad & 1) * 4;
#pragma unroll
        for (int t = 0; t < 8; ++t) {
            int p0 = t * 16 + quad * 4;
            f32x4 bv = *(const f32x4*)(b1 + p0);
            u16x4 hp;
#pragma unroll
            for (int i = 0; i < 4; ++i) hp[i] = f2bf(fmaxf(acc[t][i] + bv[i], 0.f));
            *(u16x4*)(Xs + ((p0 >> 3) * 64 + row) * 8 + j0) = hp;
        }
    }
    __syncthreads();
    // stage W2
#pragma unroll
    for (int i = 0; i < 8; ++i) {
        int chunk = tid + i * 256;
        int n = chunk >> 4, gg = chunk & 15;
        *(short8*)(Ws + (gg * 128 + n) * 8) = *(const short8*)(W2t + n * 128 + gg * 8);
    }
    __syncthreads();

    // ---- MFMA 2 (swapped): lane holds out[row0+row][n0..n0+3] ----
#pragma unroll
    for (int t = 0; t < 8; ++t) acc[t] = (f32x4){0.f, 0.f, 0.f, 0.f};
#pragma unroll
    for (int kc = 0; kc < 4; ++kc) {
        int gl = kc * 4 + quad;
        short8 hb = *(const short8*)(Xs + (gl * 64 + row) * 8);
#pragma unroll
        for (int t = 0; t < 8; ++t) {
            short8 wa = *(const short8*)(Ws + (gl * 128 + t * 16 + ln) * 8);
            acc[t] = __builtin_amdgcn_mfma_f32_16x16x32_bf16(wa, hb, acc[t], 0, 0, 0);
        }
    }
    const int m = row0 + row;
#pragma unroll
    for (int t = 0; t < 8; ++t) {
        int n0 = t * 16 + quad * 4;
        f32x4 bv = *(const f32x4*)(b2 + n0);
        f32x4 gv = *(const f32x4*)(gam + n0);
        f32x4 tv = *(const f32x4*)(bet + n0);
        u16x4 op;
#pragma unroll
        for (int i = 0; i < 4; ++i) {
            float h = acc[t][i] + bv[i];
            h = gv[i] * h * INV_STD + tv[i];
            if (CONV0) h = fmaxf(h, 0.f);
            op[i] = f2bf(h);
        }
        *(u16x4*)(out + (size_t)m * 128 + n0) = op;
    }
}

// ---------------- embedding GEMM (f32 in): out = in @ W + b ----------------
__global__ __launch_bounds__(256) void gemm_embed(
    const float* __restrict__ in, const unsigned short* __restrict__ Wt,
    const float* __restrict__ bias, unsigned short* __restrict__ out_bf, int rows)
{
    __shared__ __align__(16) unsigned short Xs[16 * 64 * 8];
    __shared__ __align__(16) unsigned short Ws[16 * 128 * 8];
    int tid = threadIdx.x;
    int row0 = blockIdx.x * 64;
#pragma unroll
    for (int i = 0; i < 8; ++i) {
        int chunk = tid + i * 256;
        int n = chunk >> 4, g = chunk & 15;
        *(short8*)(Ws + (g * 128 + n) * 8) = *(const short8*)(Wt + n * 128 + g * 8);
    }
#pragma unroll
    for (int i = 0; i < 4; ++i) {
        int chunk = tid + i * 256;
        int r = chunk >> 4, g = chunk & 15;
        int gr = row0 + r;
        ushort8 v;
        if (gr < rows) {
            const float* p = in + (size_t)gr * 128 + g * 8;
            f32x4 a0 = *(const f32x4*)p;
            f32x4 a1 = *(const f32x4*)(p + 4);
#pragma unroll
            for (int j = 0; j < 4; ++j) { v[j] = f2bf(a0[j]); v[4 + j] = f2bf(a1[j]); }
        } else {
#pragma unroll
            for (int j = 0; j < 8; ++j) v[j] = 0;
        }
        *(ushort8*)(Xs + (g * 64 + r) * 8) = v;
    }
    __syncthreads();
    int wave = tid >> 6, lane = tid & 63;
    int m0 = wave * 16;
    int ln = lane & 15, quad = lane >> 4;
    f32x4 acc[8];
#pragma unroll
    for (int t = 0; t < 8; ++t) acc[t] = (f32x4){0.f, 0.f, 0.f, 0.f};
#pragma unroll
    for (int kc = 0; kc < 4; ++kc) {
        int g = kc * 4 + quad;
        short8 a = *(const short8*)(Xs + (g * 64 + m0 + ln) * 8);
#pragma unroll
        for (int t = 0; t < 8; ++t) {
            short8 b = *(const short8*)(Ws + (g * 128 + t * 16 + ln) * 8);
            acc[t] = __builtin_amdgcn_mfma_f32_16x16x32_bf16(a, b, acc[t], 0, 0, 0);
        }
    }
#pragma unroll
    for (int t = 0; t < 8; ++t) {
        int col = t * 16 + ln;
        float bi = bias[col];
#pragma unroll
        for (int i = 0; i < 4; ++i) {
            int gr = row0 + m0 + quad * 4 + i;
            if (gr < rows) out_bf[(size_t)gr * 128 + col] = f2bf(acc[t][i] + bi);
        }
    }
}

// ---------------- y projection: y[r][10] (+)= nx[r][:] @ Wp ----------------
template<bool ACCUM>
__global__ __launch_bounds__(256) void proj_y(
    const unsigned short* __restrict__ nx, const float* __restrict__ Wp,
    float* __restrict__ y, int rows)
{
    __shared__ float Wl[HID * NCLS];
    for (int i = threadIdx.x; i < HID * NCLS; i += 256) Wl[i] = Wp[i];
    __syncthreads();
    int r = blockIdx.x * 256 + threadIdx.x;
    if (r >= rows) return;
    float acc[NCLS];
#pragma unroll
    for (int c = 0; c < NCLS; ++c) acc[c] = 0.f;
    const unsigned short* xp = nx + (size_t)r * 128;
#pragma unroll 4
    for (int g = 0; g < 16; ++g) {
        ushort8 u = *(const ushort8*)(xp + g * 8);
#pragma unroll
        for (int j = 0; j < 8; ++j) {
            float xv = bf2f(u[j]);
            const float* w = Wl + (g * 8 + j) * NCLS;
#pragma unroll
            for (int c = 0; c < NCLS; ++c) acc[c] += xv * w[c];
        }
    }
    float* yp = y + (size_t)r * NCLS;
#pragma unroll
    for (int c = 0; c < NCLS; ++c) {
        if (ACCUM) yp[c] += acc[c];
        else yp[c] = acc[c];
    }
}

// ---------------- score scatter: score[b][:] += y[ori[m]][:] ----------------
__global__ __launch_bounds__(256) void score_scatter(
    const float* __restrict__ y, const int* __restrict__ ori,
    const int* __restrict__ batch, float* __restrict__ score)
{
    __shared__ float sc[NBATCH * NCLS];
    for (int i = threadIdx.x; i < NBATCH * NCLS; i += 256) sc[i] = 0.f;
    __syncthreads();
    int stride = gridDim.x * 256;
    for (int m = blockIdx.x * 256 + threadIdx.x; m < M_COPIES; m += stride) {
        int r = ori[m], b = batch[m];
        const float* yp = y + (size_t)r * NCLS;
#pragma unroll
        for (int c = 0; c < NCLS; ++c)
            __hip_atomic_fetch_add(&sc[b * NCLS + c], yp[c],
                                   __ATOMIC_RELAXED, __HIP_MEMORY_SCOPE_WORKGROUP);
    }
    __syncthreads();
    for (int i = threadIdx.x; i < NBATCH * NCLS; i += 256) gatomic_add(score + i, sc[i]);
}

__global__ void score_final(const float* __restrict__ score, const float* __restrict__ bp,
                            float* __restrict__ out)
{
    int t = threadIdx.x;
    if (t >= NBATCH * NCLS) return;
    int c = t % NCLS;
    out[t] = score[t] + bp[c] + bp[NCLS + c] + bp[2 * NCLS + c];
}

__global__ void fill_sentinel(float* out, int n, float enc) {
    int t = blockIdx.x * 64 + threadIdx.x;
    if (t < n) out[t] = enc;
}

// ---------------- helpers ----------------
static inline void build_csr_edge(const int* src, const int* dst, const int* remap,
                                  int nitem, int nseg, int* off, int* part,
                                  int* srcs, int* comps, hipStream_t stream) {
    int nb = (nseg + 255) / 256;
    (void)hipMemsetAsync(off, 0, (size_t)nseg * 4, stream);
    hist_k<<<(nitem + 255) / 256, 256, 0, stream>>>(dst, nitem, off);
    scan1_k<<<nb, 256, 0, stream>>>(off, nseg, part);
    scan2_k<<<1, 256, 0, stream>>>(part, nb);
    scan3_k<<<nb, 256, 0, stream>>>(off, nseg, part);
    fill_edge_k<<<(nitem + 255) / 256, 256, 0, stream>>>(src, dst, remap, nitem, off, srcs, comps);
}
static inline void build_csr_pool(const int* seg, int nitem, int nseg,
                                  int* off, int* part, int* items, hipStream_t stream) {
    int nb = (nseg + 255) / 256;
    (void)hipMemsetAsync(off, 0, (size_t)nseg * 4, stream);
    hist_k<<<(nitem + 255) / 256, 256, 0, stream>>>(seg, nitem, off);
    scan1_k<<<nb, 256, 0, stream>>>(off, nseg, part);
    scan2_k<<<1, 256, 0, stream>>>(part, nb);
    scan3_k<<<nb, 256, 0, stream>>>(off, nseg, part);
    fill_pool_k<<<(nitem + 255) / 256, 256, 0, stream>>>(seg, nitem, off, items);
}

// ---------------- entry ----------------
extern "C" void kernel_launch(void* const* d_in, const int* in_sizes, int n_in,
                              void* d_out, int out_size, void* d_ws, size_t ws_size,
                              hipStream_t stream) {
    const float* x_N    = (const float*)d_in[0];
    const float* We     = (const float*)d_in[1];
    const float* be     = (const float*)d_in[2];
    const float* Wg     = (const float*)d_in[3];
    const float* bg     = (const float*)d_in[4];
    const float* eps_g  = (const float*)d_in[5];
    const float* gam    = (const float*)d_in[6];
    const float* bet    = (const float*)d_in[7];
    const float* Wp     = (const float*)d_in[8];
    const float* bp     = (const float*)d_in[9];
    const int* ori_node = (const int*)d_in[10];
    const int* node2edge= (const int*)d_in[11];
    const int* eiN      = (const int*)d_in[12];
    const int* ori_edge = (const int*)d_in[13];
    const int* edge2node= (const int*)d_in[14];
    const int* eiE      = (const int*)d_in[15];
    const int* batch    = (const int*)d_in[16];

    char* p = (char*)d_ws;
    auto take = [&](size_t n) { char* r = p; p += (n + 255) & ~(size_t)255; return r; };
    unsigned short* Wt  = (unsigned short*)take((size_t)17 * 16384 * 2);
    unsigned short* Xb  = (unsigned short*)take((size_t)M_COPIES * 128 * 2);
    unsigned short* Xb2 = (unsigned short*)take((size_t)M_COPIES * 128 * 2);
    unsigned short* nx  = (unsigned short*)take((size_t)N_NODES * 128 * 2);
    unsigned short* ex  = (unsigned short*)take((size_t)N_EDGES * 128 * 2);
    float* y            = (float*)take((size_t)N_NODES * NCLS * 4);
    float* score        = (float*)take((size_t)NBATCH * NCLS * 4);
    int* offN           = (int*)take((size_t)M_COPIES * 4);
    int* offE           = (int*)take((size_t)M_COPIES * 4);
    int* off_n2e        = (int*)take((size_t)N_EDGES * 4);
    int* off_e2n        = (int*)take((size_t)N_NODES * 4);
    int* srcsN          = (int*)take((size_t)L_EDGES * 4);
    int* compsN         = (int*)take((size_t)L_EDGES * 4);
    int* srcsE          = (int*)take((size_t)L_EDGES * 4);
    int* compsE         = (int*)take((size_t)L_EDGES * 4);
    int* it_n2e         = (int*)take((size_t)M_COPIES * 4);
    int* it_e2n         = (int*)take((size_t)M_COPIES * 4);
    int* part           = (int*)take((size_t)2048 * 4);
    size_t need = (size_t)(p - (char*)d_ws);
    if (need > ws_size) {
        fill_sentinel<<<(out_size + 63) / 64, 64, 0, stream>>>(
            (float*)d_out, out_size, 1.0e9f + (float)ws_size);
        return;
    }

    prep_w<<<1088, 256, 0, stream>>>(We, Wg, Wt);
    (void)hipMemsetAsync(score, 0, (size_t)NBATCH * NCLS * 4, stream);

    build_csr_edge(eiN, eiN + L_EDGES, ori_node, L_EDGES, M_COPIES, offN, part, srcsN, compsN, stream);
    build_csr_edge(eiE, eiE + L_EDGES, ori_edge, L_EDGES, M_COPIES, offE, part, srcsE, compsE, stream);
    build_csr_pool(node2edge, M_COPIES, N_EDGES, off_n2e, part, it_n2e, stream);
    build_csr_pool(edge2node, M_COPIES, N_NODES, off_e2n, part, it_e2n, stream);

    gemm_embed<<<(N_NODES + 63) / 64, 256, 0, stream>>>(x_N, Wt, be, nx, N_NODES);
    proj_y<false><<<(N_NODES + 255) / 256, 256, 0, stream>>>(nx, Wp, y, N_NODES);

    const int MBLK = M_COPIES / 64;   // 6250 blocks of 256 threads
    for (int layer = 0; layer < 2; ++layer) {
        for (int dir = 0; dir < 2; ++dir) {
            int cj0 = layer * 4 + dir * 2;
            int cj1 = cj0 + 1;
            const unsigned short* base = (dir == 0) ? nx : ex;
            const int* selfI = (dir == 0) ? ori_node : ori_edge;
            const int* offD  = (dir == 0) ? offN : offE;
            const int* srcsD = (dir == 0) ? srcsN : srcsE;
            const int* compD = (dir == 0) ? compsN : compsE;

            fused_conv<true><<<MBLK, 256, 0, stream>>>(
                base, selfI, offD, compD, eps_g + cj0,
                Wt + (size_t)(1 + cj0 * 2) * 16384, bg + (cj0 * 2) * 128,
                Wt + (size_t)(1 + cj0 * 2 + 1) * 16384, bg + (cj0 * 2 + 1) * 128,
                gam + cj0 * 128, bet + cj0 * 128, Xb);
            fused_conv<false><<<MBLK, 256, 0, stream>>>(
                Xb, nullptr, offD, srcsD, eps_g + cj1,
                Wt + (size_t)(1 + cj1 * 2) * 16384, bg + (cj1 * 2) * 128,
                Wt + (size_t)(1 + cj1 * 2 + 1) * 16384, bg + (cj1 * 2 + 1) * 128,
                gam + cj1 * 128, bet + cj1 * 128, Xb2);
            if (dir == 0) {
                segsum_pool<<<(N_EDGES + 15) / 16, 256, 0, stream>>>(
                    (const unsigned*)Xb2, off_n2e, it_n2e, (unsigned*)ex, N_EDGES);
            } else {
                segsum_pool<<<(N_NODES + 15) / 16, 256, 0, stream>>>(
                    (const unsigned*)Xb2, off_e2n, it_e2n, (unsigned*)nx, N_NODES);
                proj_y<true><<<(N_NODES + 255) / 256, 256, 0, stream>>>(
                    nx, Wp + (layer + 1) * HID * NCLS, y, N_NODES);
            }
        }
    }
    score_scatter<<<256, 256, 0, stream>>>(y, ori_node, batch, score);
    score_final<<<1, 320, 0, stream>>>(score, bp, (float*)d_out);
}

// Round 12
// 1741.037 us; speedup vs baseline: 1.1981x; 1.0654x over previous
//
#include <hip/hip_runtime.h>
#include <hip/hip_bf16.h>

// ---------------- problem constants ----------------
#define HID 128
static const int N_NODES = 50000;
static const int N_EDGES = 20000;
static const int M_COPIES = 400000;
static const int L_EDGES = 800000;
static const int NBATCH = 32;
static const int NCLS = 10;
#define INV_STD 0.9999950000374997f   // 1/sqrt(1+1e-5)
#define IDX_CAP 768                   // fused_conv per-block item cap (avg 128, 56 sigma)
#define POOL_CAP 2048                 // segsum_pool per-block item cap

typedef __attribute__((ext_vector_type(4))) float f32x4;
typedef __attribute__((ext_vector_type(8))) short short8;      // 8 bf16 lanes
typedef __attribute__((ext_vector_type(8))) unsigned short ushort8;
typedef __attribute__((ext_vector_type(4))) unsigned short u16x4;  // 'ushort4' collides with HIP header

__device__ __forceinline__ float bf2f(unsigned short u) {
    union { unsigned u; float f; } v; v.u = ((unsigned)u) << 16; return v.f;
}
__device__ __forceinline__ unsigned short f2bf(float f) {
    union { float f; unsigned u; } v; v.f = f;
    unsigned r = v.u + 0x7FFFu + ((v.u >> 16) & 1u);   // RNE
    return (unsigned short)(r >> 16);
}
__device__ __forceinline__ void gatomic_add(float* p, float v) {
    unsafeAtomicAdd(p, v);
}

// ---------------- weight prep: Wt[mat][n][k] = bf16(W[mat][k][n]) ----------------
__global__ __launch_bounds__(256) void prep_w(const float* __restrict__ We,
                                              const float* __restrict__ Wg,
                                              unsigned short* __restrict__ Wt) {
    int t = blockIdx.x * 256 + threadIdx.x;       // 17*16384
    if (t >= 17 * 16384) return;
    int mat = t >> 14, rem = t & 16383;
    int n = rem >> 7, k = rem & 127;
    const float* src = (mat == 0) ? We : (Wg + (size_t)(mat - 1) * 16384);
    Wt[t] = f2bf(src[k * 128 + n]);
}

// ---------------- CSR build ----------------
__global__ __launch_bounds__(256) void hist_k(const int* __restrict__ idx, int n,
                                              int* __restrict__ cnt) {
    int t = blockIdx.x * 256 + threadIdx.x;
    if (t < n) atomicAdd(&cnt[idx[t]], 1);
}

__global__ __launch_bounds__(256) void scan1_k(int* __restrict__ a, int n,
                                               int* __restrict__ part) {
    __shared__ int s[256];
    int i = blockIdx.x * 256 + threadIdx.x;
    int v = (i < n) ? a[i] : 0;
    s[threadIdx.x] = v;
    __syncthreads();
#pragma unroll
    for (int d = 1; d < 256; d <<= 1) {
        int t = (threadIdx.x >= d) ? s[threadIdx.x - d] : 0;
        __syncthreads();
        s[threadIdx.x] += t;
        __syncthreads();
    }
    if (i < n) a[i] = s[threadIdx.x] - v;
    if (threadIdx.x == 255) part[blockIdx.x] = s[255];
}

__global__ __launch_bounds__(256) void scan2_k(int* __restrict__ part, int nb) {
    __shared__ int s[256];
    __shared__ int carry;
    if (threadIdx.x == 0) carry = 0;
    __syncthreads();
    for (int base = 0; base < nb; base += 256) {
        int i = base + threadIdx.x;
        int v = (i < nb) ? part[i] : 0;
        s[threadIdx.x] = v;
        __syncthreads();
#pragma unroll
        for (int d = 1; d < 256; d <<= 1) {
            int t = (threadIdx.x >= d) ? s[threadIdx.x - d] : 0;
            __syncthreads();
            s[threadIdx.x] += t;
            __syncthreads();
        }
        if (i < nb) part[i] = carry + s[threadIdx.x] - v;
        __syncthreads();
        if (threadIdx.x == 0) carry += s[255];
        __syncthreads();
    }
}

__global__ __launch_bounds__(256) void scan3_k(int* __restrict__ a, int n,
                                               const int* __restrict__ part) {
    int i = blockIdx.x * 256 + threadIdx.x;
    if (i < n) a[i] += part[blockIdx.x];
}

__global__ __launch_bounds__(256) void fill_edge_k(
    const int* __restrict__ src, const int* __restrict__ dst,
    const int* __restrict__ remap, int n, int* __restrict__ off,
    int* __restrict__ srcs, int* __restrict__ comps) {
    int e = blockIdx.x * 256 + threadIdx.x;
    if (e >= n) return;
    int d = dst[e];
    int pos = atomicAdd(&off[d], 1);
    int s = src[e];
    srcs[pos] = s;
    comps[pos] = remap[s];
}

__global__ __launch_bounds__(256) void fill_pool_k(
    const int* __restrict__ seg, int n, int* __restrict__ off,
    int* __restrict__ items) {
    int m = blockIdx.x * 256 + threadIdx.x;
    if (m >= n) return;
    int pos = atomicAdd(&off[seg[m]], 1);
    items[pos] = m;
}

// ---------------- pool segment sum: out[m]=relu(sum tbl[items]); LDS-staged idx ----------------
__global__ __launch_bounds__(256) void segsum_pool(
    const unsigned* __restrict__ tbl, const int* __restrict__ off,
    const int* __restrict__ items, unsigned* __restrict__ out, int nseg)
{
    __shared__ int sIdx[POOL_CAP];
    int tid = threadIdx.x;
    int wave = tid >> 6, lane = tid & 63;
    int s0 = blockIdx.x * 16;
    int sN = min(s0 + 16, nseg);
    int bstart = (s0 == 0) ? 0 : off[s0 - 1];
    int bend = off[sN - 1];
    int cnt = bend - bstart;
    bool useLds = (cnt <= POOL_CAP);
    if (useLds)
        for (int i = tid; i < cnt; i += 256) sIdx[i] = items[bstart + i];
    __syncthreads();

    int mb = s0 + wave * 4;
    float a0[4] = {0.f, 0.f, 0.f, 0.f}, a1[4] = {0.f, 0.f, 0.f, 0.f};
    int pos[4], end[4];
#pragma unroll
    for (int i = 0; i < 4; ++i) {
        int m = mb + i;
        if (m < nseg) { pos[i] = (m == 0) ? 0 : off[m - 1]; end[i] = off[m]; }
        else { pos[i] = 0; end[i] = 0; }
    }
    bool more = (pos[0] < end[0]) | (pos[1] < end[1]) | (pos[2] < end[2]) | (pos[3] < end[3]);
    while (more) {
        more = false;
        unsigned v[4]; bool ld[4];
#pragma unroll
        for (int i = 0; i < 4; ++i) {
            ld[i] = pos[i] < end[i];
            if (ld[i]) {
                int r = useLds ? sIdx[pos[i] - bstart] : items[pos[i]];
                v[i] = tbl[(size_t)r * 64 + lane];
            }
        }
#pragma unroll
        for (int i = 0; i < 4; ++i) if (ld[i]) {
            a0[i] += bf2f((unsigned short)(v[i] & 0xffffu));
            a1[i] += bf2f((unsigned short)(v[i] >> 16));
            ++pos[i];
            more = more || (pos[i] < end[i]);
        }
    }
#pragma unroll
    for (int i = 0; i < 4; ++i) {
        int m = mb + i;
        if (m < nseg) {
            float r0 = fmaxf(a0[i], 0.f), r1 = fmaxf(a1[i], 0.f);
            out[(size_t)m * 64 + lane] = (unsigned)f2bf(r0) | ((unsigned)f2bf(r1) << 16);
        }
    }
}

// ---------------- fused GIN conv: 256 thr / 64 rows; split-N W staging (36 KB LDS) ----------------
// gather-segsum + linear1+ReLU + linear2+BN(+ReLU). Operand-swapped MFMAs.
// Ws holds HALF of a weight matrix (64 output channels, 16 KB) -> 4 blocks/CU.
// CONV0: self = self_idx[m], items = comps; final ReLU. !CONV0: self = m, items = srcs.
template<bool CONV0>
__global__ __launch_bounds__(256) void fused_conv(
    const unsigned short* __restrict__ tbl,
    const int* __restrict__ self_idx,
    const int* __restrict__ off, const int* __restrict__ items,
    const float* __restrict__ eps_ptr,
    const unsigned short* __restrict__ W1t, const float* __restrict__ b1,
    const unsigned short* __restrict__ W2t, const float* __restrict__ b2,
    const float* __restrict__ gam, const float* __restrict__ bet,
    unsigned short* __restrict__ out)
{
    __shared__ __align__(16) unsigned short Xs[16 * 64 * 8];  // 16 KB: [chunk][row][8]
    __shared__ __align__(16) unsigned short Ws[16 * 64 * 8];  // 16 KB: half-W [chunk][n][8]
    __shared__ int sIdx[IDX_CAP];                             // 3 KB
    __shared__ int meta[192];
    const int tid = threadIdx.x;
    const int row0 = blockIdx.x * 64;

    const int bstart = (row0 == 0) ? 0 : off[row0 - 1];
    const int cnt = off[row0 + 63] - bstart;
    const bool useLds = (cnt <= IDX_CAP);

    if (tid < 64) {
        int gr = row0 + tid;
        meta[tid]       = (gr == 0) ? 0 : off[gr - 1];
        meta[64 + tid]  = off[gr];
        meta[128 + tid] = CONV0 ? self_idx[gr] : gr;
    }
    // stage W1 half-a (out channels 0..63): 1024 chunks of 16B
#pragma unroll
    for (int i = 0; i < 4; ++i) {
        int chunk = tid + i * 256;
        int n = chunk >> 4, gg = chunk & 15;
        *(short8*)(Ws + (gg * 64 + n) * 8) = *(const short8*)(W1t + n * 128 + gg * 8);
    }
    if (useLds)
        for (int i = tid; i < cnt; i += 256) sIdx[i] = items[bstart + i];
    __syncthreads();

    // ---- gather: thread (rb,g) walks rows rb+16i; idx from LDS, 2-wide loads ----
    const float e = 1.0f + eps_ptr[0];
    const int g = tid & 15;
    const int rb = tid >> 4;        // 0..15
#pragma unroll
    for (int i = 0; i < 4; ++i) {
        int r = rb + 16 * i;
        int start = meta[r], end = meta[64 + r], self = meta[128 + r];
        float a[8];
        ushort8 u = *(const ushort8*)(tbl + (size_t)self * 128 + g * 8);
#pragma unroll
        for (int j = 0; j < 8; ++j) a[j] = e * bf2f(u[j]);
        if (useLds) {
            int pos = start - bstart, pe = end - bstart;
            for (; pos + 2 <= pe; pos += 2) {
                int i0 = sIdx[pos], i1 = sIdx[pos + 1];
                ushort8 v0 = *(const ushort8*)(tbl + (size_t)i0 * 128 + g * 8);
                ushort8 v1 = *(const ushort8*)(tbl + (size_t)i1 * 128 + g * 8);
#pragma unroll
                for (int j = 0; j < 8; ++j) a[j] += bf2f(v0[j]) + bf2f(v1[j]);
            }
            if (pos < pe) {
                int i0 = sIdx[pos];
                ushort8 v0 = *(const ushort8*)(tbl + (size_t)i0 * 128 + g * 8);
#pragma unroll
                for (int j = 0; j < 8; ++j) a[j] += bf2f(v0[j]);
            }
        } else {
            for (int pos = start; pos < end; ++pos) {
                int rr = items[pos];
                ushort8 v = *(const ushort8*)(tbl + (size_t)rr * 128 + g * 8);
#pragma unroll
                for (int j = 0; j < 8; ++j) a[j] += bf2f(v[j]);
            }
        }
        ushort8 xv;
#pragma unroll
        for (int j = 0; j < 8; ++j) xv[j] = f2bf(a[j]);
        *(ushort8*)(Xs + (g * 64 + r) * 8) = xv;
    }
    __syncthreads();

    const int wave = tid >> 6, lane = tid & 63;
    const int ln = lane & 15, quad = lane >> 4;
    const int row = wave * 16 + ln;     // wave-private X/H row (4 waves x 16 = 64)

    f32x4 acc[8];
#pragma unroll
    for (int t = 0; t < 8; ++t) acc[t] = (f32x4){0.f, 0.f, 0.f, 0.f};

    // ---- MFMA 1 half-a (channels 0..63) ----
#pragma unroll
    for (int kc = 0; kc < 4; ++kc) {
        int gl = kc * 4 + quad;
        short8 xb = *(const short8*)(Xs + (gl * 64 + row) * 8);
#pragma unroll
        for (int t = 0; t < 4; ++t) {
            short8 wa = *(const short8*)(Ws + (gl * 64 + t * 16 + ln) * 8);
            acc[t] = __builtin_amdgcn_mfma_f32_16x16x32_bf16(wa, xb, acc[t], 0, 0, 0);
        }
    }
    __syncthreads();
    // stage W1 half-b (out channels 64..127)
#pragma unroll
    for (int i = 0; i < 4; ++i) {
        int chunk = tid + i * 256;
        int n = chunk >> 4, gg = chunk & 15;
        *(short8*)(Ws + (gg * 64 + n) * 8) = *(const short8*)(W1t + (64 + n) * 128 + gg * 8);
    }
    __syncthreads();
    // ---- MFMA 1 half-b (channels 64..127) ----
#pragma unroll
    for (int kc = 0; kc < 4; ++kc) {
        int gl = kc * 4 + quad;
        short8 xb = *(const short8*)(Xs + (gl * 64 + row) * 8);
#pragma unroll
        for (int t = 0; t < 4; ++t) {
            short8 wa = *(const short8*)(Ws + (gl * 64 + t * 16 + ln) * 8);
            acc[4 + t] = __builtin_amdgcn_mfma_f32_16x16x32_bf16(wa, xb, acc[4 + t], 0, 0, 0);
        }
    }
    // h = relu(acc + b1) -> Xs (own wave's rows; X fully consumed by this wave)
    {
        const int j0 = (quad & 1) * 4;
#pragma unroll
        for (int t = 0; t < 8; ++t) {
            int p0 = t * 16 + quad * 4;
            f32x4 bv = *(const f32x4*)(b1 + p0);
            u16x4 hp;
#pragma unroll
            for (int i = 0; i < 4; ++i) hp[i] = f2bf(fmaxf(acc[t][i] + bv[i], 0.f));
            *(u16x4*)(Xs + ((p0 >> 3) * 64 + row) * 8 + j0) = hp;
        }
    }
    __syncthreads();
    // stage W2 half-a
#pragma unroll
    for (int i = 0; i < 4; ++i) {
        int chunk = tid + i * 256;
        int n = chunk >> 4, gg = chunk & 15;
        *(short8*)(Ws + (gg * 64 + n) * 8) = *(const short8*)(W2t + n * 128 + gg * 8);
    }
    __syncthreads();

#pragma unroll
    for (int t = 0; t < 8; ++t) acc[t] = (f32x4){0.f, 0.f, 0.f, 0.f};
    // ---- MFMA 2 half-a ----
#pragma unroll
    for (int kc = 0; kc < 4; ++kc) {
        int gl = kc * 4 + quad;
        short8 hb = *(const short8*)(Xs + (gl * 64 + row) * 8);
#pragma unroll
        for (int t = 0; t < 4; ++t) {
            short8 wa = *(const short8*)(Ws + (gl * 64 + t * 16 + ln) * 8);
            acc[t] = __builtin_amdgcn_mfma_f32_16x16x32_bf16(wa, hb, acc[t], 0, 0, 0);
        }
    }
    __syncthreads();
    // stage W2 half-b
#pragma unroll
    for (int i = 0; i < 4; ++i) {
        int chunk = tid + i * 256;
        int n = chunk >> 4, gg = chunk & 15;
        *(short8*)(Ws + (gg * 64 + n) * 8) = *(const short8*)(W2t + (64 + n) * 128 + gg * 8);
    }
    __syncthreads();
    // ---- MFMA 2 half-b ----
#pragma unroll
    for (int kc = 0; kc < 4; ++kc) {
        int gl = kc * 4 + quad;
        short8 hb = *(const short8*)(Xs + (gl * 64 + row) * 8);
#pragma unroll
        for (int t = 0; t < 4; ++t) {
            short8 wa = *(const short8*)(Ws + (gl * 64 + t * 16 + ln) * 8);
            acc[4 + t] = __builtin_amdgcn_mfma_f32_16x16x32_bf16(wa, hb, acc[4 + t], 0, 0, 0);
        }
    }
    // epilogue: lane holds out[row0+row][n0..n0+3] -> 8B stores
    const int m = row0 + row;
#pragma unroll
    for (int t = 0; t < 8; ++t) {
        int n0 = t * 16 + quad * 4;
        f32x4 bv = *(const f32x4*)(b2 + n0);
        f32x4 gv = *(const f32x4*)(gam + n0);
        f32x4 tv = *(const f32x4*)(bet + n0);
        u16x4 op;
#pragma unroll
        for (int i = 0; i < 4; ++i) {
            float h = acc[t][i] + bv[i];
            h = gv[i] * h * INV_STD + tv[i];
            if (CONV0) h = fmaxf(h, 0.f);
            op[i] = f2bf(h);
        }
        *(u16x4*)(out + (size_t)m * 128 + n0) = op;
    }
}

// ---------------- embedding GEMM (f32 in): out = in @ W + b ----------------
__global__ __launch_bounds__(256) void gemm_embed(
    const float* __restrict__ in, const unsigned short* __restrict__ Wt,
    const float* __restrict__ bias, unsigned short* __restrict__ out_bf, int rows)
{
    __shared__ __align__(16) unsigned short Xs[16 * 64 * 8];
    __shared__ __align__(16) unsigned short Ws[16 * 128 * 8];
    int tid = threadIdx.x;
    int row0 = blockIdx.x * 64;
#pragma unroll
    for (int i = 0; i < 8; ++i) {
        int chunk = tid + i * 256;
        int n = chunk >> 4, g = chunk & 15;
        *(short8*)(Ws + (g * 128 + n) * 8) = *(const short8*)(Wt + n * 128 + g * 8);
    }
#pragma unroll
    for (int i = 0; i < 4; ++i) {
        int chunk = tid + i * 256;
        int r = chunk >> 4, g = chunk & 15;
        int gr = row0 + r;
        ushort8 v;
        if (gr < rows) {
            const float* p = in + (size_t)gr * 128 + g * 8;
            f32x4 a0 = *(const f32x4*)p;
            f32x4 a1 = *(const f32x4*)(p + 4);
#pragma unroll
            for (int j = 0; j < 4; ++j) { v[j] = f2bf(a0[j]); v[4 + j] = f2bf(a1[j]); }
        } else {
#pragma unroll
            for (int j = 0; j < 8; ++j) v[j] = 0;
        }
        *(ushort8*)(Xs + (g * 64 + r) * 8) = v;
    }
    __syncthreads();
    int wave = tid >> 6, lane = tid & 63;
    int m0 = wave * 16;
    int ln = lane & 15, quad = lane >> 4;
    f32x4 acc[8];
#pragma unroll
    for (int t = 0; t < 8; ++t) acc[t] = (f32x4){0.f, 0.f, 0.f, 0.f};
#pragma unroll
    for (int kc = 0; kc < 4; ++kc) {
        int g = kc * 4 + quad;
        short8 a = *(const short8*)(Xs + (g * 64 + m0 + ln) * 8);
#pragma unroll
        for (int t = 0; t < 8; ++t) {
            short8 b = *(const short8*)(Ws + (g * 128 + t * 16 + ln) * 8);
            acc[t] = __builtin_amdgcn_mfma_f32_16x16x32_bf16(a, b, acc[t], 0, 0, 0);
        }
    }
#pragma unroll
    for (int t = 0; t < 8; ++t) {
        int col = t * 16 + ln;
        float bi = bias[col];
#pragma unroll
        for (int i = 0; i < 4; ++i) {
            int gr = row0 + m0 + quad * 4 + i;
            if (gr < rows) out_bf[(size_t)gr * 128 + col] = f2bf(acc[t][i] + bi);
        }
    }
}

// ---------------- y projection: y[r][10] (+)= nx[r][:] @ Wp ----------------
template<bool ACCUM>
__global__ __launch_bounds__(256) void proj_y(
    const unsigned short* __restrict__ nx, const float* __restrict__ Wp,
    float* __restrict__ y, int rows)
{
    __shared__ float Wl[HID * NCLS];
    for (int i = threadIdx.x; i < HID * NCLS; i += 256) Wl[i] = Wp[i];
    __syncthreads();
    int r = blockIdx.x * 256 + threadIdx.x;
    if (r >= rows) return;
    float acc[NCLS];
#pragma unroll
    for (int c = 0; c < NCLS; ++c) acc[c] = 0.f;
    const unsigned short* xp = nx + (size_t)r * 128;
#pragma unroll 4
    for (int g = 0; g < 16; ++g) {
        ushort8 u = *(const ushort8*)(xp + g * 8);
#pragma unroll
        for (int j = 0; j < 8; ++j) {
            float xv = bf2f(u[j]);
            const float* w = Wl + (g * 8 + j) * NCLS;
#pragma unroll
            for (int c = 0; c < NCLS; ++c) acc[c] += xv * w[c];
        }
    }
    float* yp = y + (size_t)r * NCLS;
#pragma unroll
    for (int c = 0; c < NCLS; ++c) {
        if (ACCUM) yp[c] += acc[c];
        else yp[c] = acc[c];
    }
}

// ---------------- score scatter: score[b][:] += y[ori[m]][:] ----------------
__global__ __launch_bounds__(256) void score_scatter(
    const float* __restrict__ y, const int* __restrict__ ori,
    const int* __restrict__ batch, float* __restrict__ score)
{
    __shared__ float sc[NBATCH * NCLS];
    for (int i = threadIdx.x; i < NBATCH * NCLS; i += 256) sc[i] = 0.f;
    __syncthreads();
    int stride = gridDim.x * 256;
    for (int m = blockIdx.x * 256 + threadIdx.x; m < M_COPIES; m += stride) {
        int r = ori[m], b = batch[m];
        const float* yp = y + (size_t)r * NCLS;
#pragma unroll
        for (int c = 0; c < NCLS; ++c)
            __hip_atomic_fetch_add(&sc[b * NCLS + c], yp[c],
                                   __ATOMIC_RELAXED, __HIP_MEMORY_SCOPE_WORKGROUP);
    }
    __syncthreads();
    for (int i = threadIdx.x; i < NBATCH * NCLS; i += 256) gatomic_add(score + i, sc[i]);
}

__global__ void score_final(const float* __restrict__ score, const float* __restrict__ bp,
                            float* __restrict__ out)
{
    int t = threadIdx.x;
    if (t >= NBATCH * NCLS) return;
    int c = t % NCLS;
    out[t] = score[t] + bp[c] + bp[NCLS + c] + bp[2 * NCLS + c];
}

__global__ void fill_sentinel(float* out, int n, float enc) {
    int t = blockIdx.x * 64 + threadIdx.x;
    if (t < n) out[t] = enc;
}

// ---------------- helpers ----------------
static inline void build_csr_edge(const int* src, const int* dst, const int* remap,
                                  int nitem, int nseg, int* off, int* part,
                                  int* srcs, int* comps, hipStream_t stream) {
    int nb = (nseg + 255) / 256;
    (void)hipMemsetAsync(off, 0, (size_t)nseg * 4, stream);
    hist_k<<<(nitem + 255) / 256, 256, 0, stream>>>(dst, nitem, off);
    scan1_k<<<nb, 256, 0, stream>>>(off, nseg, part);
    scan2_k<<<1, 256, 0, stream>>>(part, nb);
    scan3_k<<<nb, 256, 0, stream>>>(off, nseg, part);
    fill_edge_k<<<(nitem + 255) / 256, 256, 0, stream>>>(src, dst, remap, nitem, off, srcs, comps);
}
static inline void build_csr_pool(const int* seg, int nitem, int nseg,
                                  int* off, int* part, int* items, hipStream_t stream) {
    int nb = (nseg + 255) / 256;
    (void)hipMemsetAsync(off, 0, (size_t)nseg * 4, stream);
    hist_k<<<(nitem + 255) / 256, 256, 0, stream>>>(seg, nitem, off);
    scan1_k<<<nb, 256, 0, stream>>>(off, nseg, part);
    scan2_k<<<1, 256, 0, stream>>>(part, nb);
    scan3_k<<<nb, 256, 0, stream>>>(off, nseg, part);
    fill_pool_k<<<(nitem + 255) / 256, 256, 0, stream>>>(seg, nitem, off, items);
}

// ---------------- entry ----------------
extern "C" void kernel_launch(void* const* d_in, const int* in_sizes, int n_in,
                              void* d_out, int out_size, void* d_ws, size_t ws_size,
                              hipStream_t stream) {
    const float* x_N    = (const float*)d_in[0];
    const float* We     = (const float*)d_in[1];
    const float* be     = (const float*)d_in[2];
    const float* Wg     = (const float*)d_in[3];
    const float* bg     = (const float*)d_in[4];
    const float* eps_g  = (const float*)d_in[5];
    const float* gam    = (const float*)d_in[6];
    const float* bet    = (const float*)d_in[7];
    const float* Wp     = (const float*)d_in[8];
    const float* bp     = (const float*)d_in[9];
    const int* ori_node = (const int*)d_in[10];
    const int* node2edge= (const int*)d_in[11];
    const int* eiN      = (const int*)d_in[12];
    const int* ori_edge = (const int*)d_in[13];
    const int* edge2node= (const int*)d_in[14];
    const int* eiE      = (const int*)d_in[15];
    const int* batch    = (const int*)d_in[16];

    char* p = (char*)d_ws;
    auto take = [&](size_t n) { char* r = p; p += (n + 255) & ~(size_t)255; return r; };
    unsigned short* Wt  = (unsigned short*)take((size_t)17 * 16384 * 2);
    unsigned short* Xb  = (unsigned short*)take((size_t)M_COPIES * 128 * 2);
    unsigned short* Xb2 = (unsigned short*)take((size_t)M_COPIES * 128 * 2);
    unsigned short* nx  = (unsigned short*)take((size_t)N_NODES * 128 * 2);
    unsigned short* ex  = (unsigned short*)take((size_t)N_EDGES * 128 * 2);
    float* y            = (float*)take((size_t)N_NODES * NCLS * 4);
    float* score        = (float*)take((size_t)NBATCH * NCLS * 4);
    int* offN           = (int*)take((size_t)M_COPIES * 4);
    int* offE           = (int*)take((size_t)M_COPIES * 4);
    int* off_n2e        = (int*)take((size_t)N_EDGES * 4);
    int* off_e2n        = (int*)take((size_t)N_NODES * 4);
    int* srcsN          = (int*)take((size_t)L_EDGES * 4);
    int* compsN         = (int*)take((size_t)L_EDGES * 4);
    int* srcsE          = (int*)take((size_t)L_EDGES * 4);
    int* compsE         = (int*)take((size_t)L_EDGES * 4);
    int* it_n2e         = (int*)take((size_t)M_COPIES * 4);
    int* it_e2n         = (int*)take((size_t)M_COPIES * 4);
    int* part           = (int*)take((size_t)2048 * 4);
    size_t need = (size_t)(p - (char*)d_ws);
    if (need > ws_size) {
        fill_sentinel<<<(out_size + 63) / 64, 64, 0, stream>>>(
            (float*)d_out, out_size, 1.0e9f + (float)ws_size);
        return;
    }

    prep_w<<<1088, 256, 0, stream>>>(We, Wg, Wt);
    (void)hipMemsetAsync(score, 0, (size_t)NBATCH * NCLS * 4, stream);

    build_csr_edge(eiN, eiN + L_EDGES, ori_node, L_EDGES, M_COPIES, offN, part, srcsN, compsN, stream);
    build_csr_edge(eiE, eiE + L_EDGES, ori_edge, L_EDGES, M_COPIES, offE, part, srcsE, compsE, stream);
    build_csr_pool(node2edge, M_COPIES, N_EDGES, off_n2e, part, it_n2e, stream);
    build_csr_pool(edge2node, M_COPIES, N_NODES, off_e2n, part, it_e2n, stream);

    gemm_embed<<<(N_NODES + 63) / 64, 256, 0, stream>>>(x_N, Wt, be, nx, N_NODES);
    proj_y<false><<<(N_NODES + 255) / 256, 256, 0, stream>>>(nx, Wp, y, N_NODES);

    const int MBLK = M_COPIES / 64;   // 6250 blocks of 256 threads
    for (int layer = 0; layer < 2; ++layer) {
        for (int dir = 0; dir < 2; ++dir) {
            int cj0 = layer * 4 + dir * 2;
            int cj1 = cj0 + 1;
            const unsigned short* base = (dir == 0) ? nx : ex;
            const int* selfI = (dir == 0) ? ori_node : ori_edge;
            const int* offD  = (dir == 0) ? offN : offE;
            const int* srcsD = (dir == 0) ? srcsN : srcsE;
            const int* compD = (dir == 0) ? compsN : compsE;

            fused_conv<true><<<MBLK, 256, 0, stream>>>(
                base, selfI, offD, compD, eps_g + cj0,
                Wt + (size_t)(1 + cj0 * 2) * 16384, bg + (cj0 * 2) * 128,
                Wt + (size_t)(1 + cj0 * 2 + 1) * 16384, bg + (cj0 * 2 + 1) * 128,
                gam + cj0 * 128, bet + cj0 * 128, Xb);
            fused_conv<false><<<MBLK, 256, 0, stream>>>(
                Xb, nullptr, offD, srcsD, eps_g + cj1,
                Wt + (size_t)(1 + cj1 * 2) * 16384, bg + (cj1 * 2) * 128,
                Wt + (size_t)(1 + cj1 * 2 + 1) * 16384, bg + (cj1 * 2 + 1) * 128,
                gam + cj1 * 128, bet + cj1 * 128, Xb2);
            if (dir == 0) {
                segsum_pool<<<(N_EDGES + 15) / 16, 256, 0, stream>>>(
                    (const unsigned*)Xb2, off_n2e, it_n2e, (unsigned*)ex, N_EDGES);
            } else {
                segsum_pool<<<(N_NODES + 15) / 16, 256, 0, stream>>>(
                    (const unsigned*)Xb2, off_e2n, it_e2n, (unsigned*)nx, N_NODES);
                proj_y<true><<<(N_NODES + 255) / 256, 256, 0, stream>>>(
                    nx, Wp + (layer + 1) * HID * NCLS, y, N_NODES);
            }
        }
    }
    score_scatter<<<256, 256, 0, stream>>>(y, ori_node, batch, score);
    score_final<<<1, 320, 0, stream>>>(score, bp, (float*)d_out);
}

// Round 13
// 1636.478 us; speedup vs baseline: 1.2747x; 1.0639x over previous
//
#include <hip/hip_runtime.h>
#include <hip/hip_bf16.h>

// ---------------- problem constants ----------------
#define HID 128
static const int N_NODES = 50000;
static const int N_EDGES = 20000;
static const int M_COPIES = 400000;
static const int L_EDGES = 800000;
static const int NBATCH = 32;
static const int NCLS = 10;
#define INV_STD 0.9999950000374997f   // 1/sqrt(1+1e-5)
#define IDX_CAP 384                   // per-block item cap (avg 128, +22 sigma; global fallback)
#define POOL_CAP 2048                 // segsum_pool per-block item cap

typedef __attribute__((ext_vector_type(4))) float f32x4;
typedef __attribute__((ext_vector_type(8))) short short8;      // 8 bf16 lanes
typedef __attribute__((ext_vector_type(8))) unsigned short ushort8;
typedef __attribute__((ext_vector_type(4))) unsigned short u16x4;  // 'ushort4' collides with HIP header

__device__ __forceinline__ float bf2f(unsigned short u) {
    union { unsigned u; float f; } v; v.u = ((unsigned)u) << 16; return v.f;
}
__device__ __forceinline__ unsigned short f2bf(float f) {
    union { float f; unsigned u; } v; v.f = f;
    unsigned r = v.u + 0x7FFFu + ((v.u >> 16) & 1u);   // RNE
    return (unsigned short)(r >> 16);
}
__device__ __forceinline__ void gatomic_add(float* p, float v) {
    unsafeAtomicAdd(p, v);
}

// MFMA over one quarter of W (32 out-channels staged in Ws as [chunk][n(0..31)][8])
template<int H>
__device__ __forceinline__ void mfma_quarter(const unsigned short* Ws, const short8* xv,
                                             f32x4* acc, int quad, int ln) {
#pragma unroll
    for (int kc = 0; kc < 4; ++kc) {
#pragma unroll
        for (int tt = 0; tt < 2; ++tt) {
            short8 wa = *(const short8*)(Ws + (((kc * 4 + quad) * 32) + tt * 16 + ln) * 8);
            acc[H * 2 + tt] = __builtin_amdgcn_mfma_f32_16x16x32_bf16(wa, xv[kc], acc[H * 2 + tt], 0, 0, 0);
        }
    }
}

// ---------------- weight prep: Wt[mat][n][k] = bf16(W[mat][k][n]) ----------------
__global__ __launch_bounds__(256) void prep_w(const float* __restrict__ We,
                                              const float* __restrict__ Wg,
                                              unsigned short* __restrict__ Wt) {
    int t = blockIdx.x * 256 + threadIdx.x;       // 17*16384
    if (t >= 17 * 16384) return;
    int mat = t >> 14, rem = t & 16383;
    int n = rem >> 7, k = rem & 127;
    const float* src = (mat == 0) ? We : (Wg + (size_t)(mat - 1) * 16384);
    Wt[t] = f2bf(src[k * 128 + n]);
}

// ---------------- CSR build ----------------
__global__ __launch_bounds__(256) void hist_k(const int* __restrict__ idx, int n,
                                              int* __restrict__ cnt) {
    int t = blockIdx.x * 256 + threadIdx.x;
    if (t < n) atomicAdd(&cnt[idx[t]], 1);
}

__global__ __launch_bounds__(256) void scan1_k(int* __restrict__ a, int n,
                                               int* __restrict__ part) {
    __shared__ int s[256];
    int i = blockIdx.x * 256 + threadIdx.x;
    int v = (i < n) ? a[i] : 0;
    s[threadIdx.x] = v;
    __syncthreads();
#pragma unroll
    for (int d = 1; d < 256; d <<= 1) {
        int t = (threadIdx.x >= d) ? s[threadIdx.x - d] : 0;
        __syncthreads();
        s[threadIdx.x] += t;
        __syncthreads();
    }
    if (i < n) a[i] = s[threadIdx.x] - v;
    if (threadIdx.x == 255) part[blockIdx.x] = s[255];
}

__global__ __launch_bounds__(256) void scan2_k(int* __restrict__ part, int nb) {
    __shared__ int s[256];
    __shared__ int carry;
    if (threadIdx.x == 0) carry = 0;
    __syncthreads();
    for (int base = 0; base < nb; base += 256) {
        int i = base + threadIdx.x;
        int v = (i < nb) ? part[i] : 0;
        s[threadIdx.x] = v;
        __syncthreads();
#pragma unroll
        for (int d = 1; d < 256; d <<= 1) {
            int t = (threadIdx.x >= d) ? s[threadIdx.x - d] : 0;
            __syncthreads();
            s[threadIdx.x] += t;
            __syncthreads();
        }
        if (i < nb) part[i] = carry + s[threadIdx.x] - v;
        __syncthreads();
        if (threadIdx.x == 0) carry += s[255];
        __syncthreads();
    }
}

__global__ __launch_bounds__(256) void scan3_k(int* __restrict__ a, int n,
                                               const int* __restrict__ part) {
    int i = blockIdx.x * 256 + threadIdx.x;
    if (i < n) a[i] += part[blockIdx.x];
}

__global__ __launch_bounds__(256) void fill_edge_k(
    const int* __restrict__ src, const int* __restrict__ dst,
    const int* __restrict__ remap, int n, int* __restrict__ off,
    int* __restrict__ srcs, int* __restrict__ comps) {
    int e = blockIdx.x * 256 + threadIdx.x;
    if (e >= n) return;
    int d = dst[e];
    int pos = atomicAdd(&off[d], 1);
    int s = src[e];
    srcs[pos] = s;
    comps[pos] = remap[s];
}

__global__ __launch_bounds__(256) void fill_pool_k(
    const int* __restrict__ seg, int n, int* __restrict__ off,
    int* __restrict__ items) {
    int m = blockIdx.x * 256 + threadIdx.x;
    if (m >= n) return;
    int pos = atomicAdd(&off[seg[m]], 1);
    items[pos] = m;
}

// ---------------- pool segment sum: out[m]=relu(sum tbl[items]); LDS-staged idx ----------------
__global__ __launch_bounds__(256) void segsum_pool(
    const unsigned* __restrict__ tbl, const int* __restrict__ off,
    const int* __restrict__ items, unsigned* __restrict__ out, int nseg)
{
    __shared__ int sIdx[POOL_CAP];
    int tid = threadIdx.x;
    int wave = tid >> 6, lane = tid & 63;
    int s0 = blockIdx.x * 16;
    int sN = min(s0 + 16, nseg);
    int bstart = (s0 == 0) ? 0 : off[s0 - 1];
    int bend = off[sN - 1];
    int cnt = bend - bstart;
    bool useLds = (cnt <= POOL_CAP);
    if (useLds)
        for (int i = tid; i < cnt; i += 256) sIdx[i] = items[bstart + i];
    __syncthreads();

    int mb = s0 + wave * 4;
    float a0[4] = {0.f, 0.f, 0.f, 0.f}, a1[4] = {0.f, 0.f, 0.f, 0.f};
    int pos[4], end[4];
#pragma unroll
    for (int i = 0; i < 4; ++i) {
        int m = mb + i;
        if (m < nseg) { pos[i] = (m == 0) ? 0 : off[m - 1]; end[i] = off[m]; }
        else { pos[i] = 0; end[i] = 0; }
    }
    bool more = (pos[0] < end[0]) | (pos[1] < end[1]) | (pos[2] < end[2]) | (pos[3] < end[3]);
    while (more) {
        more = false;
        unsigned v[4]; bool ld[4];
#pragma unroll
        for (int i = 0; i < 4; ++i) {
            ld[i] = pos[i] < end[i];
            if (ld[i]) {
                int r = useLds ? sIdx[pos[i] - bstart] : items[pos[i]];
                v[i] = tbl[(size_t)r * 64 + lane];
            }
        }
#pragma unroll
        for (int i = 0; i < 4; ++i) if (ld[i]) {
            a0[i] += bf2f((unsigned short)(v[i] & 0xffffu));
            a1[i] += bf2f((unsigned short)(v[i] >> 16));
            ++pos[i];
            more = more || (pos[i] < end[i]);
        }
    }
#pragma unroll
    for (int i = 0; i < 4; ++i) {
        int m = mb + i;
        if (m < nseg) {
            float r0 = fmaxf(a0[i], 0.f), r1 = fmaxf(a1[i], 0.f);
            out[(size_t)m * 64 + lane] = (unsigned)f2bf(r0) | ((unsigned)f2bf(r1) << 16);
        }
    }
}

// ---------------- fused GIN conv: 256 thr / 64 rows; quarter-W staging (~26 KB LDS) ----------------
// gather-segsum + linear1+ReLU + linear2+BN(+ReLU). Operand-swapped MFMAs; X/H fragments
// hoisted to registers so LDS X reads happen once.
// CONV0: self = self_idx[m], items = comps; final ReLU. !CONV0: self = m, items = srcs.
template<bool CONV0>
__global__ __launch_bounds__(256, 6) void fused_conv(
    const unsigned short* __restrict__ tbl,
    const int* __restrict__ self_idx,
    const int* __restrict__ off, const int* __restrict__ items,
    const float* __restrict__ eps_ptr,
    const unsigned short* __restrict__ W1t, const float* __restrict__ b1,
    const unsigned short* __restrict__ W2t, const float* __restrict__ b2,
    const float* __restrict__ gam, const float* __restrict__ bet,
    unsigned short* __restrict__ out)
{
    __shared__ __align__(16) unsigned short Xs[16 * 64 * 8];  // 16 KB: [chunk][row][8]
    __shared__ __align__(16) unsigned short Ws[16 * 32 * 8];  // 8 KB: quarter-W [chunk][n][8]
    __shared__ int sIdx[IDX_CAP];                             // 1.5 KB
    __shared__ int meta[192];                                 // 0.75 KB
    const int tid = threadIdx.x;
    const int row0 = blockIdx.x * 64;

    const int bstart = (row0 == 0) ? 0 : off[row0 - 1];
    const int cnt = off[row0 + 63] - bstart;
    const bool useLds = (cnt <= IDX_CAP);

    if (tid < 64) {
        int gr = row0 + tid;
        meta[tid]       = (gr == 0) ? 0 : off[gr - 1];
        meta[64 + tid]  = off[gr];
        meta[128 + tid] = CONV0 ? self_idx[gr] : gr;
    }
    // stage W1 quarter 0 (out channels 0..31): 512 chunks of 16B
#pragma unroll
    for (int i = 0; i < 2; ++i) {
        int chunk = tid + i * 256;
        int n = chunk >> 4, gg = chunk & 15;
        *(short8*)(Ws + (gg * 32 + n) * 8) = *(const short8*)(W1t + n * 128 + gg * 8);
    }
    if (useLds)
        for (int i = tid; i < cnt; i += 256) sIdx[i] = items[bstart + i];
    __syncthreads();

    // ---- gather: thread (rb,g) walks rows rb+16i; idx from LDS, 2-wide loads ----
    const float e = 1.0f + eps_ptr[0];
    const int g = tid & 15;
    const int rb = tid >> 4;        // 0..15
#pragma unroll
    for (int i = 0; i < 4; ++i) {
        int r = rb + 16 * i;
        int start = meta[r], end = meta[64 + r], self = meta[128 + r];
        float a[8];
        ushort8 u = *(const ushort8*)(tbl + (size_t)self * 128 + g * 8);
#pragma unroll
        for (int j = 0; j < 8; ++j) a[j] = e * bf2f(u[j]);
        if (useLds) {
            int pos = start - bstart, pe = end - bstart;
            for (; pos + 2 <= pe; pos += 2) {
                int i0 = sIdx[pos], i1 = sIdx[pos + 1];
                ushort8 v0 = *(const ushort8*)(tbl + (size_t)i0 * 128 + g * 8);
                ushort8 v1 = *(const ushort8*)(tbl + (size_t)i1 * 128 + g * 8);
#pragma unroll
                for (int j = 0; j < 8; ++j) a[j] += bf2f(v0[j]) + bf2f(v1[j]);
            }
            if (pos < pe) {
                int i0 = sIdx[pos];
                ushort8 v0 = *(const ushort8*)(tbl + (size_t)i0 * 128 + g * 8);
#pragma unroll
                for (int j = 0; j < 8; ++j) a[j] += bf2f(v0[j]);
            }
        } else {
            for (int pos = start; pos < end; ++pos) {
                int rr = items[pos];
                ushort8 v = *(const ushort8*)(tbl + (size_t)rr * 128 + g * 8);
#pragma unroll
                for (int j = 0; j < 8; ++j) a[j] += bf2f(v[j]);
            }
        }
        ushort8 xv;
#pragma unroll
        for (int j = 0; j < 8; ++j) xv[j] = f2bf(a[j]);
        *(ushort8*)(Xs + (g * 64 + r) * 8) = xv;
    }
    __syncthreads();

    const int lane = tid & 63;
    const int ln = lane & 15, quad = lane >> 4;
    const int row = (tid >> 6) * 16 + ln;   // wave-private X/H row (4 waves x 16 = 64)

    // hoist X fragments (all LDS X reads happen here, before any H write)
    short8 xb[4];
#pragma unroll
    for (int kc = 0; kc < 4; ++kc)
        xb[kc] = *(const short8*)(Xs + ((kc * 4 + quad) * 64 + row) * 8);

    f32x4 acc[8];
#pragma unroll
    for (int t = 0; t < 8; ++t) acc[t] = (f32x4){0.f, 0.f, 0.f, 0.f};

    // ---- MFMA 1: quarter 0 staged; quarters 1..3 restage Ws ----
    mfma_quarter<0>(Ws, xb, acc, quad, ln);
#pragma unroll
    for (int h = 1; h < 4; ++h) {
        __syncthreads();
#pragma unroll
        for (int i = 0; i < 2; ++i) {
            int chunk = tid + i * 256;
            int n = chunk >> 4, gg = chunk & 15;
            *(short8*)(Ws + (gg * 32 + n) * 8) = *(const short8*)(W1t + (h * 32 + n) * 128 + gg * 8);
        }
        __syncthreads();
        if (h == 1) mfma_quarter<1>(Ws, xb, acc, quad, ln);
        else if (h == 2) mfma_quarter<2>(Ws, xb, acc, quad, ln);
        else mfma_quarter<3>(Ws, xb, acc, quad, ln);
    }
    // h = relu(acc + b1) -> Xs (safe: all X reads were hoisted before quarter 0)
    {
        const int j0 = (quad & 1) * 4;
#pragma unroll
        for (int t = 0; t < 8; ++t) {
            int p0 = t * 16 + quad * 4;
            f32x4 bv = *(const f32x4*)(b1 + p0);
            u16x4 hp;
#pragma unroll
            for (int i = 0; i < 4; ++i) hp[i] = f2bf(fmaxf(acc[t][i] + bv[i], 0.f));
            *(u16x4*)(Xs + ((p0 >> 3) * 64 + row) * 8 + j0) = hp;
        }
    }
    __syncthreads();
    // stage W2 quarter 0
#pragma unroll
    for (int i = 0; i < 2; ++i) {
        int chunk = tid + i * 256;
        int n = chunk >> 4, gg = chunk & 15;
        *(short8*)(Ws + (gg * 32 + n) * 8) = *(const short8*)(W2t + n * 128 + gg * 8);
    }
    __syncthreads();

    // hoist H fragments
    short8 hb[4];
#pragma unroll
    for (int kc = 0; kc < 4; ++kc)
        hb[kc] = *(const short8*)(Xs + ((kc * 4 + quad) * 64 + row) * 8);

#pragma unroll
    for (int t = 0; t < 8; ++t) acc[t] = (f32x4){0.f, 0.f, 0.f, 0.f};

    mfma_quarter<0>(Ws, hb, acc, quad, ln);
#pragma unroll
    for (int h = 1; h < 4; ++h) {
        __syncthreads();
#pragma unroll
        for (int i = 0; i < 2; ++i) {
            int chunk = tid + i * 256;
            int n = chunk >> 4, gg = chunk & 15;
            *(short8*)(Ws + (gg * 32 + n) * 8) = *(const short8*)(W2t + (h * 32 + n) * 128 + gg * 8);
        }
        __syncthreads();
        if (h == 1) mfma_quarter<1>(Ws, hb, acc, quad, ln);
        else if (h == 2) mfma_quarter<2>(Ws, hb, acc, quad, ln);
        else mfma_quarter<3>(Ws, hb, acc, quad, ln);
    }

    // epilogue: lane holds out[row0+row][n0..n0+3] -> 8B stores
    const int m = row0 + row;
#pragma unroll
    for (int t = 0; t < 8; ++t) {
        int n0 = t * 16 + quad * 4;
        f32x4 bv = *(const f32x4*)(b2 + n0);
        f32x4 gv = *(const f32x4*)(gam + n0);
        f32x4 tv = *(const f32x4*)(bet + n0);
        u16x4 op;
#pragma unroll
        for (int i = 0; i < 4; ++i) {
            float h = acc[t][i] + bv[i];
            h = gv[i] * h * INV_STD + tv[i];
            if (CONV0) h = fmaxf(h, 0.f);
            op[i] = f2bf(h);
        }
        *(u16x4*)(out + (size_t)m * 128 + n0) = op;
    }
}

// ---------------- embedding GEMM (f32 in): out = in @ W + b ----------------
__global__ __launch_bounds__(256) void gemm_embed(
    const float* __restrict__ in, const unsigned short* __restrict__ Wt,
    const float* __restrict__ bias, unsigned short* __restrict__ out_bf, int rows)
{
    __shared__ __align__(16) unsigned short Xs[16 * 64 * 8];
    __shared__ __align__(16) unsigned short Ws[16 * 128 * 8];
    int tid = threadIdx.x;
    int row0 = blockIdx.x * 64;
#pragma unroll
    for (int i = 0; i < 8; ++i) {
        int chunk = tid + i * 256;
        int n = chunk >> 4, g = chunk & 15;
        *(short8*)(Ws + (g * 128 + n) * 8) = *(const short8*)(Wt + n * 128 + g * 8);
    }
#pragma unroll
    for (int i = 0; i < 4; ++i) {
        int chunk = tid + i * 256;
        int r = chunk >> 4, g = chunk & 15;
        int gr = row0 + r;
        ushort8 v;
        if (gr < rows) {
            const float* p = in + (size_t)gr * 128 + g * 8;
            f32x4 a0 = *(const f32x4*)p;
            f32x4 a1 = *(const f32x4*)(p + 4);
#pragma unroll
            for (int j = 0; j < 4; ++j) { v[j] = f2bf(a0[j]); v[4 + j] = f2bf(a1[j]); }
        } else {
#pragma unroll
            for (int j = 0; j < 8; ++j) v[j] = 0;
        }
        *(ushort8*)(Xs + (g * 64 + r) * 8) = v;
    }
    __syncthreads();
    int wave = tid >> 6, lane = tid & 63;
    int m0 = wave * 16;
    int ln = lane & 15, quad = lane >> 4;
    f32x4 acc[8];
#pragma unroll
    for (int t = 0; t < 8; ++t) acc[t] = (f32x4){0.f, 0.f, 0.f, 0.f};
#pragma unroll
    for (int kc = 0; kc < 4; ++kc) {
        int g = kc * 4 + quad;
        short8 a = *(const short8*)(Xs + (g * 64 + m0 + ln) * 8);
#pragma unroll
        for (int t = 0; t < 8; ++t) {
            short8 b = *(const short8*)(Ws + (g * 128 + t * 16 + ln) * 8);
            acc[t] = __builtin_amdgcn_mfma_f32_16x16x32_bf16(a, b, acc[t], 0, 0, 0);
        }
    }
#pragma unroll
    for (int t = 0; t < 8; ++t) {
        int col = t * 16 + ln;
        float bi = bias[col];
#pragma unroll
        for (int i = 0; i < 4; ++i) {
            int gr = row0 + m0 + quad * 4 + i;
            if (gr < rows) out_bf[(size_t)gr * 128 + col] = f2bf(acc[t][i] + bi);
        }
    }
}

// ---------------- y projection: y[r][10] (+)= nx[r][:] @ Wp ----------------
template<bool ACCUM>
__global__ __launch_bounds__(256) void proj_y(
    const unsigned short* __restrict__ nx, const float* __restrict__ Wp,
    float* __restrict__ y, int rows)
{
    __shared__ float Wl[HID * NCLS];
    for (int i = threadIdx.x; i < HID * NCLS; i += 256) Wl[i] = Wp[i];
    __syncthreads();
    int r = blockIdx.x * 256 + threadIdx.x;
    if (r >= rows) return;
    float acc[NCLS];
#pragma unroll
    for (int c = 0; c < NCLS; ++c) acc[c] = 0.f;
    const unsigned short* xp = nx + (size_t)r * 128;
#pragma unroll 4
    for (int g = 0; g < 16; ++g) {
        ushort8 u = *(const ushort8*)(xp + g * 8);
#pragma unroll
        for (int j = 0; j < 8; ++j) {
            float xv = bf2f(u[j]);
            const float* w = Wl + (g * 8 + j) * NCLS;
#pragma unroll
            for (int c = 0; c < NCLS; ++c) acc[c] += xv * w[c];
        }
    }
    float* yp = y + (size_t)r * NCLS;
#pragma unroll
    for (int c = 0; c < NCLS; ++c) {
        if (ACCUM) yp[c] += acc[c];
        else yp[c] = acc[c];
    }
}

// ---------------- score scatter: score[b][:] += y[ori[m]][:] ----------------
__global__ __launch_bounds__(256) void score_scatter(
    const float* __restrict__ y, const int* __restrict__ ori,
    const int* __restrict__ batch, float* __restrict__ score)
{
    __shared__ float sc[NBATCH * NCLS];
    for (int i = threadIdx.x; i < NBATCH * NCLS; i += 256) sc[i] = 0.f;
    __syncthreads();
    int stride = gridDim.x * 256;
    for (int m = blockIdx.x * 256 + threadIdx.x; m < M_COPIES; m += stride) {
        int r = ori[m], b = batch[m];
        const float* yp = y + (size_t)r * NCLS;
#pragma unroll
        for (int c = 0; c < NCLS; ++c)
            __hip_atomic_fetch_add(&sc[b * NCLS + c], yp[c],
                                   __ATOMIC_RELAXED, __HIP_MEMORY_SCOPE_WORKGROUP);
    }
    __syncthreads();
    for (int i = threadIdx.x; i < NBATCH * NCLS; i += 256) gatomic_add(score + i, sc[i]);
}

__global__ void score_final(const float* __restrict__ score, const float* __restrict__ bp,
                            float* __restrict__ out)
{
    int t = threadIdx.x;
    if (t >= NBATCH * NCLS) return;
    int c = t % NCLS;
    out[t] = score[t] + bp[c] + bp[NCLS + c] + bp[2 * NCLS + c];
}

__global__ void fill_sentinel(float* out, int n, float enc) {
    int t = blockIdx.x * 64 + threadIdx.x;
    if (t < n) out[t] = enc;
}

// ---------------- helpers ----------------
static inline void build_csr_edge(const int* src, const int* dst, const int* remap,
                                  int nitem, int nseg, int* off, int* part,
                                  int* srcs, int* comps, hipStream_t stream) {
    int nb = (nseg + 255) / 256;
    (void)hipMemsetAsync(off, 0, (size_t)nseg * 4, stream);
    hist_k<<<(nitem + 255) / 256, 256, 0, stream>>>(dst, nitem, off);
    scan1_k<<<nb, 256, 0, stream>>>(off, nseg, part);
    scan2_k<<<1, 256, 0, stream>>>(part, nb);
    scan3_k<<<nb, 256, 0, stream>>>(off, nseg, part);
    fill_edge_k<<<(nitem + 255) / 256, 256, 0, stream>>>(src, dst, remap, nitem, off, srcs, comps);
}
static inline void build_csr_pool(const int* seg, int nitem, int nseg,
                                  int* off, int* part, int* items, hipStream_t stream) {
    int nb = (nseg + 255) / 256;
    (void)hipMemsetAsync(off, 0, (size_t)nseg * 4, stream);
    hist_k<<<(nitem + 255) / 256, 256, 0, stream>>>(seg, nitem, off);
    scan1_k<<<nb, 256, 0, stream>>>(off, nseg, part);
    scan2_k<<<1, 256, 0, stream>>>(part, nb);
    scan3_k<<<nb, 256, 0, stream>>>(off, nseg, part);
    fill_pool_k<<<(nitem + 255) / 256, 256, 0, stream>>>(seg, nitem, off, items);
}

// ---------------- entry ----------------
extern "C" void kernel_launch(void* const* d_in, const int* in_sizes, int n_in,
                              void* d_out, int out_size, void* d_ws, size_t ws_size,
                              hipStream_t stream) {
    const float* x_N    = (const float*)d_in[0];
    const float* We     = (const float*)d_in[1];
    const float* be     = (const float*)d_in[2];
    const float* Wg     = (const float*)d_in[3];
    const float* bg     = (const float*)d_in[4];
    const float* eps_g  = (const float*)d_in[5];
    const float* gam    = (const float*)d_in[6];
    const float* bet    = (const float*)d_in[7];
    const float* Wp     = (const float*)d_in[8];
    const float* bp     = (const float*)d_in[9];
    const int* ori_node = (const int*)d_in[10];
    const int* node2edge= (const int*)d_in[11];
    const int* eiN      = (const int*)d_in[12];
    const int* ori_edge = (const int*)d_in[13];
    const int* edge2node= (const int*)d_in[14];
    const int* eiE      = (const int*)d_in[15];
    const int* batch    = (const int*)d_in[16];

    char* p = (char*)d_ws;
    auto take = [&](size_t n) { char* r = p; p += (n + 255) & ~(size_t)255; return r; };
    unsigned short* Wt  = (unsigned short*)take((size_t)17 * 16384 * 2);
    unsigned short* Xb  = (unsigned short*)take((size_t)M_COPIES * 128 * 2);
    unsigned short* Xb2 = (unsigned short*)take((size_t)M_COPIES * 128 * 2);
    unsigned short* nx  = (unsigned short*)take((size_t)N_NODES * 128 * 2);
    unsigned short* ex  = (unsigned short*)take((size_t)N_EDGES * 128 * 2);
    float* y            = (float*)take((size_t)N_NODES * NCLS * 4);
    float* score        = (float*)take((size_t)NBATCH * NCLS * 4);
    int* offN           = (int*)take((size_t)M_COPIES * 4);
    int* offE           = (int*)take((size_t)M_COPIES * 4);
    int* off_n2e        = (int*)take((size_t)N_EDGES * 4);
    int* off_e2n        = (int*)take((size_t)N_NODES * 4);
    int* srcsN          = (int*)take((size_t)L_EDGES * 4);
    int* compsN         = (int*)take((size_t)L_EDGES * 4);
    int* srcsE          = (int*)take((size_t)L_EDGES * 4);
    int* compsE         = (int*)take((size_t)L_EDGES * 4);
    int* it_n2e         = (int*)take((size_t)M_COPIES * 4);
    int* it_e2n         = (int*)take((size_t)M_COPIES * 4);
    int* part           = (int*)take((size_t)2048 * 4);
    size_t need = (size_t)(p - (char*)d_ws);
    if (need > ws_size) {
        fill_sentinel<<<(out_size + 63) / 64, 64, 0, stream>>>(
            (float*)d_out, out_size, 1.0e9f + (float)ws_size);
        return;
    }

    prep_w<<<1088, 256, 0, stream>>>(We, Wg, Wt);
    (void)hipMemsetAsync(score, 0, (size_t)NBATCH * NCLS * 4, stream);

    build_csr_edge(eiN, eiN + L_EDGES, ori_node, L_EDGES, M_COPIES, offN, part, srcsN, compsN, stream);
    build_csr_edge(eiE, eiE + L_EDGES, ori_edge, L_EDGES, M_COPIES, offE, part, srcsE, compsE, stream);
    build_csr_pool(node2edge, M_COPIES, N_EDGES, off_n2e, part, it_n2e, stream);
    build_csr_pool(edge2node, M_COPIES, N_NODES, off_e2n, part, it_e2n, stream);

    gemm_embed<<<(N_NODES + 63) / 64, 256, 0, stream>>>(x_N, Wt, be, nx, N_NODES);
    proj_y<false><<<(N_NODES + 255) / 256, 256, 0, stream>>>(nx, Wp, y, N_NODES);

    const int MBLK = M_COPIES / 64;   // 6250 blocks of 256 threads
    for (int layer = 0; layer < 2; ++layer) {
        for (int dir = 0; dir < 2; ++dir) {
            int cj0 = layer * 4 + dir * 2;
            int cj1 = cj0 + 1;
            const unsigned short* base = (dir == 0) ? nx : ex;
            const int* selfI = (dir == 0) ? ori_node : ori_edge;
            const int* offD  = (dir == 0) ? offN : offE;
            const int* srcsD = (dir == 0) ? srcsN : srcsE;
            const int* compD = (dir == 0) ? compsN : compsE;

            fused_conv<true><<<MBLK, 256, 0, stream>>>(
                base, selfI, offD, compD, eps_g + cj0,
                Wt + (size_t)(1 + cj0 * 2) * 16384, bg + (cj0 * 2) * 128,
                Wt + (size_t)(1 + cj0 * 2 + 1) * 16384, bg + (cj0 * 2 + 1) * 128,
                gam + cj0 * 128, bet + cj0 * 128, Xb);
            fused_conv<false><<<MBLK, 256, 0, stream>>>(
                Xb, nullptr, offD, srcsD, eps_g + cj1,
                Wt + (size_t)(1 + cj1 * 2) * 16384, bg + (cj1 * 2) * 128,
                Wt + (size_t)(1 + cj1 * 2 + 1) * 16384, bg + (cj1 * 2 + 1) * 128,
                gam + cj1 * 128, bet + cj1 * 128, Xb2);
            if (dir == 0) {
                segsum_pool<<<(N_EDGES + 15) / 16, 256, 0, stream>>>(
                    (const unsigned*)Xb2, off_n2e, it_n2e, (unsigned*)ex, N_EDGES);
            } else {
                segsum_pool<<<(N_NODES + 15) / 16, 256, 0, stream>>>(
                    (const unsigned*)Xb2, off_e2n, it_e2n, (unsigned*)nx, N_NODES);
                proj_y<true><<<(N_NODES + 255) / 256, 256, 0, stream>>>(
                    nx, Wp + (layer + 1) * HID * NCLS, y, N_NODES);
            }
        }
    }
    score_scatter<<<256, 256, 0, stream>>>(y, ori_node, batch, score);
    score_final<<<1, 320, 0, stream>>>(score, bp, (float*)d_out);
}

// Round 14
// 1527.070 us; speedup vs baseline: 1.3660x; 1.0716x over previous
//
#include <hip/hip_runtime.h>
#include <hip/hip_bf16.h>

// ---------------- problem constants ----------------
#define HID 128
static const int N_NODES = 50000;
static const int N_EDGES = 20000;
static const int M_COPIES = 400000;
static const int L_EDGES = 800000;
static const int NBATCH = 32;
static const int NCLS = 10;
#define INV_STD 0.9999950000374997f   // 1/sqrt(1+1e-5)
#define IDX_CAP 384                   // per-block item cap (avg 128; global fallback)

typedef __attribute__((ext_vector_type(4))) float f32x4;
typedef __attribute__((ext_vector_type(8))) short short8;      // 8 bf16 lanes
typedef __attribute__((ext_vector_type(8))) unsigned short ushort8;
typedef __attribute__((ext_vector_type(4))) unsigned short u16x4;  // 'ushort4' collides with HIP header

__device__ __forceinline__ float bf2f(unsigned short u) {
    union { unsigned u; float f; } v; v.u = ((unsigned)u) << 16; return v.f;
}
__device__ __forceinline__ unsigned short f2bf(float f) {
    union { float f; unsigned u; } v; v.f = f;
    unsigned r = v.u + 0x7FFFu + ((v.u >> 16) & 1u);   // RNE
    return (unsigned short)(r >> 16);
}
__device__ __forceinline__ void gatomic_add(float* p, float v) {
    unsafeAtomicAdd(p, v);
}

// MFMA over one EIGHTH of W (16 out-channels staged in Ws as [chunk][n(0..15)][8])
template<int H>
__device__ __forceinline__ void mfma_eighth(const unsigned short* Ws, const short8* xv,
                                            f32x4* acc, int quad, int ln) {
#pragma unroll
    for (int kc = 0; kc < 4; ++kc) {
        short8 wa = *(const short8*)(Ws + (((kc * 4 + quad) * 16) + ln) * 8);
        acc[H] = __builtin_amdgcn_mfma_f32_16x16x32_bf16(wa, xv[kc], acc[H], 0, 0, 0);
    }
}

// ---------------- weight prep: Wt[mat][n][k] = bf16(W[mat][k][n]) ----------------
__global__ __launch_bounds__(256) void prep_w(const float* __restrict__ We,
                                              const float* __restrict__ Wg,
                                              unsigned short* __restrict__ Wt) {
    int t = blockIdx.x * 256 + threadIdx.x;       // 17*16384
    if (t >= 17 * 16384) return;
    int mat = t >> 14, rem = t & 16383;
    int n = rem >> 7, k = rem & 127;
    const float* src = (mat == 0) ? We : (Wg + (size_t)(mat - 1) * 16384);
    Wt[t] = f2bf(src[k * 128 + n]);
}

// ---------------- CSR build ----------------
__global__ __launch_bounds__(256) void hist_k(const int* __restrict__ idx, int n,
                                              int* __restrict__ cnt) {
    int t = blockIdx.x * 256 + threadIdx.x;
    if (t < n) atomicAdd(&cnt[idx[t]], 1);
}

__global__ __launch_bounds__(256) void scan1_k(int* __restrict__ a, int n,
                                               int* __restrict__ part) {
    __shared__ int s[256];
    int i = blockIdx.x * 256 + threadIdx.x;
    int v = (i < n) ? a[i] : 0;
    s[threadIdx.x] = v;
    __syncthreads();
#pragma unroll
    for (int d = 1; d < 256; d <<= 1) {
        int t = (threadIdx.x >= d) ? s[threadIdx.x - d] : 0;
        __syncthreads();
        s[threadIdx.x] += t;
        __syncthreads();
    }
    if (i < n) a[i] = s[threadIdx.x] - v;
    if (threadIdx.x == 255) part[blockIdx.x] = s[255];
}

__global__ __launch_bounds__(256) void scan2_k(int* __restrict__ part, int nb) {
    __shared__ int s[256];
    __shared__ int carry;
    if (threadIdx.x == 0) carry = 0;
    __syncthreads();
    for (int base = 0; base < nb; base += 256) {
        int i = base + threadIdx.x;
        int v = (i < nb) ? part[i] : 0;
        s[threadIdx.x] = v;
        __syncthreads();
#pragma unroll
        for (int d = 1; d < 256; d <<= 1) {
            int t = (threadIdx.x >= d) ? s[threadIdx.x - d] : 0;
            __syncthreads();
            s[threadIdx.x] += t;
            __syncthreads();
        }
        if (i < nb) part[i] = carry + s[threadIdx.x] - v;
        __syncthreads();
        if (threadIdx.x == 0) carry += s[255];
        __syncthreads();
    }
}

__global__ __launch_bounds__(256) void scan3_k(int* __restrict__ a, int n,
                                               const int* __restrict__ part) {
    int i = blockIdx.x * 256 + threadIdx.x;
    if (i < n) a[i] += part[blockIdx.x];
}

__global__ __launch_bounds__(256) void fill_edge_k(
    const int* __restrict__ src, const int* __restrict__ dst,
    const int* __restrict__ remap, int n, int* __restrict__ off,
    int* __restrict__ srcs, int* __restrict__ comps) {
    int e = blockIdx.x * 256 + threadIdx.x;
    if (e >= n) return;
    int d = dst[e];
    int pos = atomicAdd(&off[d], 1);
    int s = src[e];
    srcs[pos] = s;
    comps[pos] = remap[s];
}

__global__ __launch_bounds__(256) void fill_pool_k(
    const int* __restrict__ seg, int n, int* __restrict__ off,
    int* __restrict__ items) {
    int m = blockIdx.x * 256 + threadIdx.x;
    if (m >= n) return;
    int pos = atomicAdd(&off[seg[m]], 1);
    items[pos] = m;
}

// ---------------- pool segment sum: wave-per-segment, 4 rows in flight ----------------
// lane (g=lane&15, sub=lane>>4): accumulates chunk g of items pos+sub; shuffle-reduce over sub.
__global__ __launch_bounds__(256) void segsum_pool(
    const unsigned short* __restrict__ tbl, const int* __restrict__ off,
    const int* __restrict__ items, unsigned short* __restrict__ out, int nseg)
{
    int wave = threadIdx.x >> 6, lane = threadIdx.x & 63;
    int seg = blockIdx.x * 4 + wave;
    if (seg >= nseg) return;
    int start = (seg == 0) ? 0 : off[seg - 1];
    int end = off[seg];
    int g = lane & 15, sub = lane >> 4;
    float a[8] = {0.f, 0.f, 0.f, 0.f, 0.f, 0.f, 0.f, 0.f};
    for (int p = start + sub; p < end; p += 4) {
        int r = items[p];                          // broadcast across the 16 g-lanes
        ushort8 v = *(const ushort8*)(tbl + (size_t)r * 128 + g * 8);
#pragma unroll
        for (int j = 0; j < 8; ++j) a[j] += bf2f(v[j]);
    }
#pragma unroll
    for (int j = 0; j < 8; ++j) {
        a[j] += __shfl_xor(a[j], 16, 64);
        a[j] += __shfl_xor(a[j], 32, 64);
    }
    if (sub == 0) {
        ushort8 ov;
#pragma unroll
        for (int j = 0; j < 8; ++j) ov[j] = f2bf(fmaxf(a[j], 0.f));
        *(ushort8*)(out + (size_t)seg * 128 + g * 8) = ov;
    }
}

// ---------------- fused GIN conv: 256 thr / 64 rows; eighth-W staging (~22 KB LDS) ----------------
// gather-segsum + linear1+ReLU + linear2+BN(+ReLU). Operand-swapped MFMAs; X/H fragments
// hoisted to registers. Ws holds 16 out-channels (4 KB) -> 7 blocks/CU target.
template<bool CONV0>
__global__ __launch_bounds__(256, 7) void fused_conv(
    const unsigned short* __restrict__ tbl,
    const int* __restrict__ self_idx,
    const int* __restrict__ off, const int* __restrict__ items,
    const float* __restrict__ eps_ptr,
    const unsigned short* __restrict__ W1t, const float* __restrict__ b1,
    const unsigned short* __restrict__ W2t, const float* __restrict__ b2,
    const float* __restrict__ gam, const float* __restrict__ bet,
    unsigned short* __restrict__ out)
{
    __shared__ __align__(16) unsigned short Xs[16 * 64 * 8];  // 16 KB: [chunk][row][8]
    __shared__ __align__(16) unsigned short Ws[16 * 16 * 8];  // 4 KB: eighth-W [chunk][n][8]
    __shared__ int sIdx[IDX_CAP];                             // 1.5 KB
    __shared__ int meta[192];                                 // 0.75 KB
    const int tid = threadIdx.x;
    const int row0 = blockIdx.x * 64;

    const int bstart = (row0 == 0) ? 0 : off[row0 - 1];
    const int cnt = off[row0 + 63] - bstart;
    const bool useLds = (cnt <= IDX_CAP);

    if (tid < 64) {
        int gr = row0 + tid;
        meta[tid]       = (gr == 0) ? 0 : off[gr - 1];
        meta[64 + tid]  = off[gr];
        meta[128 + tid] = CONV0 ? self_idx[gr] : gr;
    }
    // stage W1 eighth 0 (out channels 0..15): 256 chunks of 16B, one per thread
    {
        int n = tid >> 4, gg = tid & 15;
        *(short8*)(Ws + (gg * 16 + n) * 8) = *(const short8*)(W1t + n * 128 + gg * 8);
    }
    if (useLds)
        for (int i = tid; i < cnt; i += 256) sIdx[i] = items[bstart + i];
    __syncthreads();

    // ---- gather: thread (rb,g) walks rows rb+16i; idx from LDS, 2-wide loads ----
    const float e = 1.0f + eps_ptr[0];
    const int g = tid & 15;
    const int rb = tid >> 4;        // 0..15
#pragma unroll
    for (int i = 0; i < 4; ++i) {
        int r = rb + 16 * i;
        int start = meta[r], end = meta[64 + r], self = meta[128 + r];
        float a[8];
        ushort8 u = *(const ushort8*)(tbl + (size_t)self * 128 + g * 8);
#pragma unroll
        for (int j = 0; j < 8; ++j) a[j] = e * bf2f(u[j]);
        if (useLds) {
            int pos = start - bstart, pe = end - bstart;
            for (; pos + 2 <= pe; pos += 2) {
                int i0 = sIdx[pos], i1 = sIdx[pos + 1];
                ushort8 v0 = *(const ushort8*)(tbl + (size_t)i0 * 128 + g * 8);
                ushort8 v1 = *(const ushort8*)(tbl + (size_t)i1 * 128 + g * 8);
#pragma unroll
                for (int j = 0; j < 8; ++j) a[j] += bf2f(v0[j]) + bf2f(v1[j]);
            }
            if (pos < pe) {
                int i0 = sIdx[pos];
                ushort8 v0 = *(const ushort8*)(tbl + (size_t)i0 * 128 + g * 8);
#pragma unroll
                for (int j = 0; j < 8; ++j) a[j] += bf2f(v0[j]);
            }
        } else {
            for (int pos = start; pos < end; ++pos) {
                int rr = items[pos];
                ushort8 v = *(const ushort8*)(tbl + (size_t)rr * 128 + g * 8);
#pragma unroll
                for (int j = 0; j < 8; ++j) a[j] += bf2f(v[j]);
            }
        }
        ushort8 xv;
#pragma unroll
        for (int j = 0; j < 8; ++j) xv[j] = f2bf(a[j]);
        *(ushort8*)(Xs + (g * 64 + r) * 8) = xv;
    }
    __syncthreads();

    const int lane = tid & 63;
    const int ln = lane & 15, quad = lane >> 4;
    const int row = (tid >> 6) * 16 + ln;   // wave-private X/H row (4 waves x 16 = 64)

    // hoist X fragments (all LDS X reads happen here, before any H write)
    short8 xb[4];
#pragma unroll
    for (int kc = 0; kc < 4; ++kc)
        xb[kc] = *(const short8*)(Xs + ((kc * 4 + quad) * 64 + row) * 8);

    f32x4 acc[8];
#pragma unroll
    for (int t = 0; t < 8; ++t) acc[t] = (f32x4){0.f, 0.f, 0.f, 0.f};

    // ---- MFMA 1: eighth 0 staged; eighths 1..7 restage Ws ----
    mfma_eighth<0>(Ws, xb, acc, quad, ln);
#pragma unroll
    for (int h = 1; h < 8; ++h) {
        __syncthreads();
        {
            int n = tid >> 4, gg = tid & 15;
            *(short8*)(Ws + (gg * 16 + n) * 8) = *(const short8*)(W1t + (h * 16 + n) * 128 + gg * 8);
        }
        __syncthreads();
        switch (h) {
            case 1: mfma_eighth<1>(Ws, xb, acc, quad, ln); break;
            case 2: mfma_eighth<2>(Ws, xb, acc, quad, ln); break;
            case 3: mfma_eighth<3>(Ws, xb, acc, quad, ln); break;
            case 4: mfma_eighth<4>(Ws, xb, acc, quad, ln); break;
            case 5: mfma_eighth<5>(Ws, xb, acc, quad, ln); break;
            case 6: mfma_eighth<6>(Ws, xb, acc, quad, ln); break;
            default: mfma_eighth<7>(Ws, xb, acc, quad, ln); break;
        }
    }
    // h = relu(acc + b1) -> Xs (safe: all X reads were hoisted)
    {
        const int j0 = (quad & 1) * 4;
#pragma unroll
        for (int t = 0; t < 8; ++t) {
            int p0 = t * 16 + quad * 4;
            f32x4 bv = *(const f32x4*)(b1 + p0);
            u16x4 hp;
#pragma unroll
            for (int i = 0; i < 4; ++i) hp[i] = f2bf(fmaxf(acc[t][i] + bv[i], 0.f));
            *(u16x4*)(Xs + ((p0 >> 3) * 64 + row) * 8 + j0) = hp;
        }
    }
    __syncthreads();
    // stage W2 eighth 0
    {
        int n = tid >> 4, gg = tid & 15;
        *(short8*)(Ws + (gg * 16 + n) * 8) = *(const short8*)(W2t + n * 128 + gg * 8);
    }
    __syncthreads();

    // hoist H fragments
    short8 hb[4];
#pragma unroll
    for (int kc = 0; kc < 4; ++kc)
        hb[kc] = *(const short8*)(Xs + ((kc * 4 + quad) * 64 + row) * 8);

#pragma unroll
    for (int t = 0; t < 8; ++t) acc[t] = (f32x4){0.f, 0.f, 0.f, 0.f};

    mfma_eighth<0>(Ws, hb, acc, quad, ln);
#pragma unroll
    for (int h = 1; h < 8; ++h) {
        __syncthreads();
        {
            int n = tid >> 4, gg = tid & 15;
            *(short8*)(Ws + (gg * 16 + n) * 8) = *(const short8*)(W2t + (h * 16 + n) * 128 + gg * 8);
        }
        __syncthreads();
        switch (h) {
            case 1: mfma_eighth<1>(Ws, hb, acc, quad, ln); break;
            case 2: mfma_eighth<2>(Ws, hb, acc, quad, ln); break;
            case 3: mfma_eighth<3>(Ws, hb, acc, quad, ln); break;
            case 4: mfma_eighth<4>(Ws, hb, acc, quad, ln); break;
            case 5: mfma_eighth<5>(Ws, hb, acc, quad, ln); break;
            case 6: mfma_eighth<6>(Ws, hb, acc, quad, ln); break;
            default: mfma_eighth<7>(Ws, hb, acc, quad, ln); break;
        }
    }

    // epilogue: lane holds out[row0+row][n0..n0+3] -> 8B stores
    const int m = row0 + row;
#pragma unroll
    for (int t = 0; t < 8; ++t) {
        int n0 = t * 16 + quad * 4;
        f32x4 bv = *(const f32x4*)(b2 + n0);
        f32x4 gv = *(const f32x4*)(gam + n0);
        f32x4 tv = *(const f32x4*)(bet + n0);
        u16x4 op;
#pragma unroll
        for (int i = 0; i < 4; ++i) {
            float h = acc[t][i] + bv[i];
            h = gv[i] * h * INV_STD + tv[i];
            if (CONV0) h = fmaxf(h, 0.f);
            op[i] = f2bf(h);
        }
        *(u16x4*)(out + (size_t)m * 128 + n0) = op;
    }
}

// ---------------- embedding GEMM (f32 in): out = in @ W + b ----------------
__global__ __launch_bounds__(256) void gemm_embed(
    const float* __restrict__ in, const unsigned short* __restrict__ Wt,
    const float* __restrict__ bias, unsigned short* __restrict__ out_bf, int rows)
{
    __shared__ __align__(16) unsigned short Xs[16 * 64 * 8];
    __shared__ __align__(16) unsigned short Ws[16 * 128 * 8];
    int tid = threadIdx.x;
    int row0 = blockIdx.x * 64;
#pragma unroll
    for (int i = 0; i < 8; ++i) {
        int chunk = tid + i * 256;
        int n = chunk >> 4, g = chunk & 15;
        *(short8*)(Ws + (g * 128 + n) * 8) = *(const short8*)(Wt + n * 128 + g * 8);
    }
#pragma unroll
    for (int i = 0; i < 4; ++i) {
        int chunk = tid + i * 256;
        int r = chunk >> 4, g = chunk & 15;
        int gr = row0 + r;
        ushort8 v;
        if (gr < rows) {
            const float* p = in + (size_t)gr * 128 + g * 8;
            f32x4 a0 = *(const f32x4*)p;
            f32x4 a1 = *(const f32x4*)(p + 4);
#pragma unroll
            for (int j = 0; j < 4; ++j) { v[j] = f2bf(a0[j]); v[4 + j] = f2bf(a1[j]); }
        } else {
#pragma unroll
            for (int j = 0; j < 8; ++j) v[j] = 0;
        }
        *(ushort8*)(Xs + (g * 64 + r) * 8) = v;
    }
    __syncthreads();
    int wave = tid >> 6, lane = tid & 63;
    int m0 = wave * 16;
    int ln = lane & 15, quad = lane >> 4;
    f32x4 acc[8];
#pragma unroll
    for (int t = 0; t < 8; ++t) acc[t] = (f32x4){0.f, 0.f, 0.f, 0.f};
#pragma unroll
    for (int kc = 0; kc < 4; ++kc) {
        int g = kc * 4 + quad;
        short8 a = *(const short8*)(Xs + (g * 64 + m0 + ln) * 8);
#pragma unroll
        for (int t = 0; t < 8; ++t) {
            short8 b = *(const short8*)(Ws + (g * 128 + t * 16 + ln) * 8);
            acc[t] = __builtin_amdgcn_mfma_f32_16x16x32_bf16(a, b, acc[t], 0, 0, 0);
        }
    }
#pragma unroll
    for (int t = 0; t < 8; ++t) {
        int col = t * 16 + ln;
        float bi = bias[col];
#pragma unroll
        for (int i = 0; i < 4; ++i) {
            int gr = row0 + m0 + quad * 4 + i;
            if (gr < rows) out_bf[(size_t)gr * 128 + col] = f2bf(acc[t][i] + bi);
        }
    }
}

// ---------------- y projection: y[r][10] (+)= nx[r][:] @ Wp ----------------
template<bool ACCUM>
__global__ __launch_bounds__(256) void proj_y(
    const unsigned short* __restrict__ nx, const float* __restrict__ Wp,
    float* __restrict__ y, int rows)
{
    __shared__ float Wl[HID * NCLS];
    for (int i = threadIdx.x; i < HID * NCLS; i += 256) Wl[i] = Wp[i];
    __syncthreads();
    int r = blockIdx.x * 256 + threadIdx.x;
    if (r >= rows) return;
    float acc[NCLS];
#pragma unroll
    for (int c = 0; c < NCLS; ++c) acc[c] = 0.f;
    const unsigned short* xp = nx + (size_t)r * 128;
#pragma unroll 4
    for (int g = 0; g < 16; ++g) {
        ushort8 u = *(const ushort8*)(xp + g * 8);
#pragma unroll
        for (int j = 0; j < 8; ++j) {
            float xv = bf2f(u[j]);
            const float* w = Wl + (g * 8 + j) * NCLS;
#pragma unroll
            for (int c = 0; c < NCLS; ++c) acc[c] += xv * w[c];
        }
    }
    float* yp = y + (size_t)r * NCLS;
#pragma unroll
    for (int c = 0; c < NCLS; ++c) {
        if (ACCUM) yp[c] += acc[c];
        else yp[c] = acc[c];
    }
}

// ---------------- score scatter: score[b][:] += y[ori[m]][:] ----------------
__global__ __launch_bounds__(256) void score_scatter(
    const float* __restrict__ y, const int* __restrict__ ori,
    const int* __restrict__ batch, float* __restrict__ score)
{
    __shared__ float sc[NBATCH * NCLS];
    for (int i = threadIdx.x; i < NBATCH * NCLS; i += 256) sc[i] = 0.f;
    __syncthreads();
    int stride = gridDim.x * 256;
    for (int m = blockIdx.x * 256 + threadIdx.x; m < M_COPIES; m += stride) {
        int r = ori[m], b = batch[m];
        const float* yp = y + (size_t)r * NCLS;
#pragma unroll
        for (int c = 0; c < NCLS; ++c)
            __hip_atomic_fetch_add(&sc[b * NCLS + c], yp[c],
                                   __ATOMIC_RELAXED, __HIP_MEMORY_SCOPE_WORKGROUP);
    }
    __syncthreads();
    for (int i = threadIdx.x; i < NBATCH * NCLS; i += 256) gatomic_add(score + i, sc[i]);
}

__global__ void score_final(const float* __restrict__ score, const float* __restrict__ bp,
                            float* __restrict__ out)
{
    int t = threadIdx.x;
    if (t >= NBATCH * NCLS) return;
    int c = t % NCLS;
    out[t] = score[t] + bp[c] + bp[NCLS + c] + bp[2 * NCLS + c];
}

__global__ void fill_sentinel(float* out, int n, float enc) {
    int t = blockIdx.x * 64 + threadIdx.x;
    if (t < n) out[t] = enc;
}

// ---------------- helpers ----------------
static inline void build_csr_edge(const int* src, const int* dst, const int* remap,
                                  int nitem, int nseg, int* off, int* part,
                                  int* srcs, int* comps, hipStream_t stream) {
    int nb = (nseg + 255) / 256;
    (void)hipMemsetAsync(off, 0, (size_t)nseg * 4, stream);
    hist_k<<<(nitem + 255) / 256, 256, 0, stream>>>(dst, nitem, off);
    scan1_k<<<nb, 256, 0, stream>>>(off, nseg, part);
    scan2_k<<<1, 256, 0, stream>>>(part, nb);
    scan3_k<<<nb, 256, 0, stream>>>(off, nseg, part);
    fill_edge_k<<<(nitem + 255) / 256, 256, 0, stream>>>(src, dst, remap, nitem, off, srcs, comps);
}
static inline void build_csr_pool(const int* seg, int nitem, int nseg,
                                  int* off, int* part, int* items, hipStream_t stream) {
    int nb = (nseg + 255) / 256;
    (void)hipMemsetAsync(off, 0, (size_t)nseg * 4, stream);
    hist_k<<<(nitem + 255) / 256, 256, 0, stream>>>(seg, nitem, off);
    scan1_k<<<nb, 256, 0, stream>>>(off, nseg, part);
    scan2_k<<<1, 256, 0, stream>>>(part, nb);
    scan3_k<<<nb, 256, 0, stream>>>(off, nseg, part);
    fill_pool_k<<<(nitem + 255) / 256, 256, 0, stream>>>(seg, nitem, off, items);
}

// ---------------- entry ----------------
extern "C" void kernel_launch(void* const* d_in, const int* in_sizes, int n_in,
                              void* d_out, int out_size, void* d_ws, size_t ws_size,
                              hipStream_t stream) {
    const float* x_N    = (const float*)d_in[0];
    const float* We     = (const float*)d_in[1];
    const float* be     = (const float*)d_in[2];
    const float* Wg     = (const float*)d_in[3];
    const float* bg     = (const float*)d_in[4];
    const float* eps_g  = (const float*)d_in[5];
    const float* gam    = (const float*)d_in[6];
    const float* bet    = (const float*)d_in[7];
    const float* Wp     = (const float*)d_in[8];
    const float* bp     = (const float*)d_in[9];
    const int* ori_node = (const int*)d_in[10];
    const int* node2edge= (const int*)d_in[11];
    const int* eiN      = (const int*)d_in[12];
    const int* ori_edge = (const int*)d_in[13];
    const int* edge2node= (const int*)d_in[14];
    const int* eiE      = (const int*)d_in[15];
    const int* batch    = (const int*)d_in[16];

    char* p = (char*)d_ws;
    auto take = [&](size_t n) { char* r = p; p += (n + 255) & ~(size_t)255; return r; };
    unsigned short* Wt  = (unsigned short*)take((size_t)17 * 16384 * 2);
    unsigned short* Xb  = (unsigned short*)take((size_t)M_COPIES * 128 * 2);
    unsigned short* Xb2 = (unsigned short*)take((size_t)M_COPIES * 128 * 2);
    unsigned short* nx  = (unsigned short*)take((size_t)N_NODES * 128 * 2);
    unsigned short* ex  = (unsigned short*)take((size_t)N_EDGES * 128 * 2);
    float* y            = (float*)take((size_t)N_NODES * NCLS * 4);
    float* score        = (float*)take((size_t)NBATCH * NCLS * 4);
    int* offN           = (int*)take((size_t)M_COPIES * 4);
    int* offE           = (int*)take((size_t)M_COPIES * 4);
    int* off_n2e        = (int*)take((size_t)N_EDGES * 4);
    int* off_e2n        = (int*)take((size_t)N_NODES * 4);
    int* srcsN          = (int*)take((size_t)L_EDGES * 4);
    int* compsN         = (int*)take((size_t)L_EDGES * 4);
    int* srcsE          = (int*)take((size_t)L_EDGES * 4);
    int* compsE         = (int*)take((size_t)L_EDGES * 4);
    int* it_n2e         = (int*)take((size_t)M_COPIES * 4);
    int* it_e2n         = (int*)take((size_t)M_COPIES * 4);
    int* part           = (int*)take((size_t)2048 * 4);
    size_t need = (size_t)(p - (char*)d_ws);
    if (need > ws_size) {
        fill_sentinel<<<(out_size + 63) / 64, 64, 0, stream>>>(
            (float*)d_out, out_size, 1.0e9f + (float)ws_size);
        return;
    }

    prep_w<<<1088, 256, 0, stream>>>(We, Wg, Wt);
    (void)hipMemsetAsync(score, 0, (size_t)NBATCH * NCLS * 4, stream);

    build_csr_edge(eiN, eiN + L_EDGES, ori_node, L_EDGES, M_COPIES, offN, part, srcsN, compsN, stream);
    build_csr_edge(eiE, eiE + L_EDGES, ori_edge, L_EDGES, M_COPIES, offE, part, srcsE, compsE, stream);
    build_csr_pool(node2edge, M_COPIES, N_EDGES, off_n2e, part, it_n2e, stream);
    build_csr_pool(edge2node, M_COPIES, N_NODES, off_e2n, part, it_e2n, stream);

    gemm_embed<<<(N_NODES + 63) / 64, 256, 0, stream>>>(x_N, Wt, be, nx, N_NODES);
    proj_y<false><<<(N_NODES + 255) / 256, 256, 0, stream>>>(nx, Wp, y, N_NODES);

    const int MBLK = M_COPIES / 64;   // 6250 blocks of 256 threads
    for (int layer = 0; layer < 2; ++layer) {
        for (int dir = 0; dir < 2; ++dir) {
            int cj0 = layer * 4 + dir * 2;
            int cj1 = cj0 + 1;
            const unsigned short* base = (dir == 0) ? nx : ex;
            const int* selfI = (dir == 0) ? ori_node : ori_edge;
            const int* offD  = (dir == 0) ? offN : offE;
            const int* srcsD = (dir == 0) ? srcsN : srcsE;
            const int* compD = (dir == 0) ? compsN : compsE;

            fused_conv<true><<<MBLK, 256, 0, stream>>>(
                base, selfI, offD, compD, eps_g + cj0,
                Wt + (size_t)(1 + cj0 * 2) * 16384, bg + (cj0 * 2) * 128,
                Wt + (size_t)(1 + cj0 * 2 + 1) * 16384, bg + (cj0 * 2 + 1) * 128,
                gam + cj0 * 128, bet + cj0 * 128, Xb);
            fused_conv<false><<<MBLK, 256, 0, stream>>>(
                Xb, nullptr, offD, srcsD, eps_g + cj1,
                Wt + (size_t)(1 + cj1 * 2) * 16384, bg + (cj1 * 2) * 128,
                Wt + (size_t)(1 + cj1 * 2 + 1) * 16384, bg + (cj1 * 2 + 1) * 128,
                gam + cj1 * 128, bet + cj1 * 128, Xb2);
            if (dir == 0) {
                segsum_pool<<<(N_EDGES + 3) / 4, 256, 0, stream>>>(
                    Xb2, off_n2e, it_n2e, ex, N_EDGES);
            } else {
                segsum_pool<<<(N_NODES + 3) / 4, 256, 0, stream>>>(
                    Xb2, off_e2n, it_e2n, nx, N_NODES);
                proj_y<true><<<(N_NODES + 255) / 256, 256, 0, stream>>>(
                    nx, Wp + (layer + 1) * HID * NCLS, y, N_NODES);
            }
        }
    }
    score_scatter<<<256, 256, 0, stream>>>(y, ori_node, batch, score);
    score_final<<<1, 320, 0, stream>>>(score, bp, (float*)d_out);
}